// Round 6
// baseline (2487.101 us; speedup 1.0000x reference)
//
#include <hip/hip_runtime.h>
#include <hip/hip_bf16.h>
#include <math.h>

#define D_MODEL 512
#define N_HEADS 8
#define D_HEAD  64
#define D_FF    2048
#define SEQ     512
#define BATCH   8
#define ROWS    (BATCH * SEQ)          /* 4096 */
#define PRED_LEN 96
#define KLEN_MASKED (SEQ - PRED_LEN)   /* 416 */
#define LN_EPS  1e-5f

typedef float  f32x4 __attribute__((ext_vector_type(4)));
typedef short  s16x8 __attribute__((ext_vector_type(8)));

__device__ __forceinline__ float bf2f(ushort u) {
    union { unsigned int i; float f; } c; c.i = ((unsigned int)u) << 16; return c.f;
}
__device__ __forceinline__ ushort f2bf(float v) {
    __hip_bfloat16 h = __float2bfloat16(v);
    return *(ushort*)&h;
}
__device__ __forceinline__ void gl_lds16(const void* g, void* lds) {
    __builtin_amdgcn_global_load_lds(
        (const __attribute__((address_space(1))) unsigned int*)g,
        (__attribute__((address_space(3))) unsigned int*)lds, 16, 0, 0);
}

/* ============ GEMM descriptor + shared MFMA body ============================
 * C = A[M,K] @ Bt[N,K]^T + bias (opt relu). BM=128, BK=32, 4 waves 2x2.
 * VT-epilogue (validated R4): blocks with n0>=vcol0 write per-head transposed V.
 * LN tail (new R6): last col-block of a stripe does residual+LayerNorm.
 */
struct GDesc {
    const ushort* A; int lda;
    const ushort* Bt; int ldb;
    ushort* C; int ldc;
    int N; int K;
    const float* bias; int relu;
    ushort* VT; int vcol0;
    /* LN-fusion tail (only for gemm_fused) */
    const float* resid32;
    const float* gamma; const float* beta;
    float* out32; ushort* outb;
    unsigned int* cnt; int nblk;
};

template<int BN>
__device__ __forceinline__ void gemm_body(const GDesc& d)
{
    constexpr int NW = BN / 32;
    __shared__ __attribute__((aligned(16))) ushort As[128 * 32];
    __shared__ __attribute__((aligned(16))) ushort Bs[BN * 32];
    const int tid = threadIdx.x;
    const int w = tid >> 6, lane = tid & 63;
    const int l16 = lane & 15, quad = lane >> 4;
    const int m0 = blockIdx.y * 128, n0 = blockIdx.x * BN;
    const ushort* Ab = d.A + (size_t)m0 * d.lda;
    const ushort* Bb = d.Bt + (size_t)n0 * d.ldb;
    const int wm = (w >> 1) * 64, wn = (w & 1) * (BN / 2);
    const int K = d.K;

    f32x4 acc[4][NW];
    #pragma unroll
    for (int i = 0; i < 4; ++i)
        #pragma unroll
        for (int j = 0; j < NW; ++j) acc[i][j] = (f32x4)0.f;

    for (int k0 = 0; k0 < K; k0 += 32) {
        #pragma unroll
        for (int t = 0; t < 2; ++t) {
            int c = (t * 4 + w) * 64 + lane;
            gl_lds16(Ab + (size_t)(c >> 2) * d.lda + k0 + (c & 3) * 8,
                     (void*)(As + (size_t)(t * 4 + w) * 512));
        }
        #pragma unroll
        for (int t = 0; t < BN / 64; ++t) {
            int c = (t * 4 + w) * 64 + lane;
            gl_lds16(Bb + (size_t)(c >> 2) * d.ldb + k0 + (c & 3) * 8,
                     (void*)(Bs + (size_t)(t * 4 + w) * 512));
        }
        __syncthreads();
        s16x8 af[4];
        #pragma unroll
        for (int i = 0; i < 4; ++i)
            af[i] = *(const s16x8*)(As + (size_t)(wm + i * 16 + l16) * 32 + quad * 8);
        #pragma unroll
        for (int j = 0; j < NW; ++j) {
            s16x8 bfr = *(const s16x8*)(Bs + (size_t)(wn + j * 16 + l16) * 32 + quad * 8);
            #pragma unroll
            for (int i = 0; i < 4; ++i)
                acc[i][j] = __builtin_amdgcn_mfma_f32_16x16x32_bf16(af[i], bfr, acc[i][j], 0, 0, 0);
        }
        __syncthreads();
    }
    const bool isv = (d.VT != nullptr) && (n0 >= d.vcol0);
    if (isv) {
        #pragma unroll
        for (int i = 0; i < 4; ++i) {
            int mrow = m0 + wm + i * 16 + quad * 4;
            int b = mrow >> 9, pbase = mrow & 511;
            #pragma unroll
            for (int j = 0; j < NW; ++j) {
                int cv = n0 + wn + j * 16 + l16 - d.vcol0;   /* 0..511 */
                int h = cv >> 6, dd = cv & 63;
                union { ushort u[4]; uint2 v; } pk;
                #pragma unroll
                for (int r = 0; r < 4; ++r) pk.u[r] = f2bf(acc[i][j][r]);
                *(uint2*)(d.VT + ((size_t)((b * 8 + h) * 64 + dd) * 512 + pbase)) = pk.v;
            }
        }
    } else {
        #pragma unroll
        for (int i = 0; i < 4; ++i) {
            #pragma unroll
            for (int j = 0; j < NW; ++j) {
                int col = n0 + wn + j * 16 + l16;
                float bv = d.bias ? d.bias[col] : 0.f;
                #pragma unroll
                for (int r = 0; r < 4; ++r) {
                    float v = acc[i][j][r] + bv;
                    if (d.relu) v = fmaxf(v, 0.f);
                    d.C[(size_t)(m0 + wm + i * 16 + quad * 4 + r) * d.ldc + col] = f2bf(v);
                }
            }
        }
    }
}

template<int BN>
__global__ __launch_bounds__(256) void gemm_one(GDesc d)
{
    if ((int)(blockIdx.x * BN) < d.N) gemm_body<BN>(d);
}

__global__ __launch_bounds__(256) void gemm_two(GDesc d0, GDesc d1)
{
    const GDesc& d = blockIdx.z ? d1 : d0;
    if ((int)(blockIdx.x * 128) < d.N) gemm_body<128>(d);
}

/* GEMM + (last col-block per stripe) residual-add + LayerNorm tail */
__global__ __launch_bounds__(256) void gemm_fused(GDesc d)
{
    gemm_body<64>(d);
    __threadfence();                                   /* release: drain C stores */
    __shared__ int lastf;
    if (threadIdx.x == 0)
        lastf = (atomicAdd(d.cnt + blockIdx.y, 1u) == (unsigned)(d.nblk - 1));
    __syncthreads();
    if (!lastf) return;
    __threadfence();                                   /* acquire: inv stale L2 */
    const int w = threadIdx.x >> 6, lane = threadIdx.x & 63;
    const int m0 = blockIdx.y * 128;
    float gv[8], bv[8];
    #pragma unroll
    for (int j = 0; j < 8; ++j) {
        gv[j] = d.gamma[lane * 8 + j];
        bv[j] = d.beta[lane * 8 + j];
    }
    for (int rr = w; rr < 128; rr += 4) {
        const int row = m0 + rr;
        s16x8 cv = *(const s16x8*)(d.C + (size_t)row * d.ldc + lane * 8);
        const float* rp = d.resid32 + (size_t)row * 512 + lane * 8;
        float v[8], s1 = 0.f, s2 = 0.f;
        #pragma unroll
        for (int j = 0; j < 8; ++j) {
            float x = bf2f(((const ushort*)&cv)[j]) + rp[j];
            v[j] = x; s1 += x; s2 += x * x;
        }
        #pragma unroll
        for (int off = 1; off < 64; off <<= 1) {
            s1 += __shfl_xor(s1, off);
            s2 += __shfl_xor(s2, off);
        }
        float mu  = s1 * (1.f / 512.f);
        float var = s2 * (1.f / 512.f) - mu * mu;
        float rs  = rsqrtf(var + LN_EPS);
        float* o32 = d.out32 + (size_t)row * 512 + lane * 8;
        ushort ob[8];
        #pragma unroll
        for (int j = 0; j < 8; ++j) {
            float y = (v[j] - mu) * rs * gv[j] + bv[j];
            o32[j] = y;
            ob[j] = f2bf(y);
        }
        *(s16x8*)(d.outb + (size_t)row * 512 + lane * 8) = *(const s16x8*)ob;
    }
}

/* ============ flash attention: O = softmax(Q K^T / 8, klen) V =============== */
__global__ __launch_bounds__(256) void flash_attn(
    const ushort* __restrict__ Q, int ldq,
    const ushort* __restrict__ K, int ldk,
    const ushort* __restrict__ Vt,
    ushort* __restrict__ O, int ldo, int klen)
{
    __shared__ __attribute__((aligned(16))) ushort KVs[8192];
    __shared__ __attribute__((aligned(16))) ushort Es[4][2048];
    const int tid = threadIdx.x, w = tid >> 6, lane = tid & 63;
    const int l16 = lane & 15, quad = lane >> 4;
    const int bh = blockIdx.y, b = bh >> 3, h = bh & 7;
    const int q0 = blockIdx.x * 64;

    const ushort* Qb = Q + (size_t)(b * SEQ) * ldq + h * D_HEAD;
    const ushort* Kb = K + (size_t)(b * SEQ) * ldk + h * D_HEAD;

    s16x8 af0, af1;
    {
        const ushort* qr = Qb + (size_t)(q0 + w * 16 + l16) * ldq + quad * 8;
        af0 = *(const s16x8*)(qr);
        af1 = *(const s16x8*)(qr + 32);
    }

    f32x4 sc[32];

    #pragma unroll
    for (int kc = 0; kc < 4; ++kc) {
        #pragma unroll
        for (int it = 0; it < 4; ++it) {
            int cc = (it * 4 + w) * 64 + lane;
            int row = cc >> 3;
            int dch = (cc & 7) ^ (row & 7);
            gl_lds16(Kb + (size_t)(kc * 128 + row) * ldk + dch * 8,
                     (void*)(KVs + (size_t)(it * 4 + w) * 512));
        }
        __syncthreads();
        #pragma unroll
        for (int kt = 0; kt < 8; ++kt) {
            int r0 = kt * 16 + l16;
            s16x8 b0 = *(const s16x8*)(KVs + r0 * 64 + ((quad)     ^ (r0 & 7)) * 8);
            s16x8 b1 = *(const s16x8*)(KVs + r0 * 64 + ((4 + quad) ^ (r0 & 7)) * 8);
            f32x4 a = __builtin_amdgcn_mfma_f32_16x16x32_bf16(af0, b0, (f32x4)0.f, 0, 0, 0);
            sc[kc * 8 + kt] = __builtin_amdgcn_mfma_f32_16x16x32_bf16(af1, b1, a, 0, 0, 0);
        }
        __syncthreads();
    }

    float inv[4];
    #pragma unroll
    for (int r = 0; r < 4; ++r) {
        float m = -1e30f;
        #pragma unroll
        for (int j = 0; j < 32; ++j) {
            bool valid = (j * 16 + l16) < klen;
            m = valid ? fmaxf(m, sc[j][r]) : m;
        }
        m = fmaxf(m, __shfl_xor(m, 1));
        m = fmaxf(m, __shfl_xor(m, 2));
        m = fmaxf(m, __shfl_xor(m, 4));
        m = fmaxf(m, __shfl_xor(m, 8));
        float ssum = 0.f;
        #pragma unroll
        for (int j = 0; j < 32; ++j) {
            bool valid = (j * 16 + l16) < klen;
            float e = valid ? __expf((sc[j][r] - m) * 0.125f) : 0.f;
            sc[j][r] = e;
            ssum += e;
        }
        ssum += __shfl_xor(ssum, 1);
        ssum += __shfl_xor(ssum, 2);
        ssum += __shfl_xor(ssum, 4);
        ssum += __shfl_xor(ssum, 8);
        inv[r] = 1.f / ssum;
    }

    f32x4 oacc[4];
    #pragma unroll
    for (int jd = 0; jd < 4; ++jd) oacc[jd] = (f32x4)0.f;
    const ushort* Vb = Vt + (size_t)bh * (D_HEAD * SEQ);
    #pragma unroll
    for (int kc = 0; kc < 4; ++kc) {
        #pragma unroll
        for (int it = 0; it < 4; ++it) {
            int cc = (it * 4 + w) * 64 + lane;
            int d = cc >> 4;
            int kch = (cc & 15) ^ (d & 15);
            gl_lds16(Vb + (size_t)d * SEQ + kc * 128 + kch * 8,
                     (void*)(KVs + (size_t)(it * 4 + w) * 512));
        }
        #pragma unroll
        for (int j = 0; j < 8; ++j) {
            int lcj = j * 2 + (l16 >> 3);
            #pragma unroll
            for (int r = 0; r < 4; ++r) {
                int m = quad * 4 + r;
                Es[w][m * 128 + (lcj ^ m) * 8 + (l16 & 7)] = f2bf(sc[kc * 8 + j][r]);
            }
        }
        __syncthreads();
        #pragma unroll
        for (int ks = 0; ks < 4; ++ks) {
            int lc = ks * 4 + quad;
            s16x8 ea = *(const s16x8*)(&Es[w][l16 * 128 + (lc ^ l16) * 8]);
            #pragma unroll
            for (int jd = 0; jd < 4; ++jd) {
                int row = jd * 16 + l16;
                s16x8 vb = *(const s16x8*)(KVs + row * 128 + (lc ^ l16) * 8);
                oacc[jd] = __builtin_amdgcn_mfma_f32_16x16x32_bf16(ea, vb, oacc[jd], 0, 0, 0);
            }
        }
        __syncthreads();
    }

    ushort* Ob = O + (size_t)(b * SEQ) * ldo + h * D_HEAD;
    #pragma unroll
    for (int jd = 0; jd < 4; ++jd)
        #pragma unroll
        for (int r = 0; r < 4; ++r)
            Ob[(size_t)(q0 + w * 16 + quad * 4 + r) * ldo + jd * 16 + l16] =
                f2bf(oacc[jd][r] * inv[r]);
}

/* ============ batched weight repacks ============ */
struct AttnPtrs { const float* p[48]; };
struct FfPtrs   { const float* p[16]; };

__global__ __launch_bounds__(256) void repack_attn(AttnPtrs L, ushort* __restrict__ out)
{
    int z = blockIdx.z;
    const float* in = L.p[z];
    ushort* o = out + (size_t)z * 262144;
    __shared__ float t[32][33];
    int n0 = blockIdx.x * 32, k0 = blockIdx.y * 32;
    int tx = threadIdx.x & 31, ty = threadIdx.x >> 5;
    #pragma unroll
    for (int r = 0; r < 4; ++r)
        t[ty + r * 8][tx] = in[(size_t)(k0 + ty + r * 8) * 512 + n0 + tx];
    __syncthreads();
    #pragma unroll
    for (int r = 0; r < 4; ++r)
        o[(size_t)(n0 + ty + r * 8) * 512 + k0 + tx] = f2bf(t[tx][ty + r * 8]);
}

__global__ __launch_bounds__(256) void repack_ff(FfPtrs L, ushort* __restrict__ out)
{
    int z = blockIdx.y;
    int Kd = (z < 8) ? 512 : 2048, Nd = (z < 8) ? 2048 : 512;
    const float* in = L.p[z];
    ushort* o = out + (size_t)z * (512 * 2048);
    int t = blockIdx.x;
    int tn = Nd / 32;
    int n0 = (t % tn) * 32, k0 = (t / tn) * 32;
    __shared__ float ts[32][33];
    int tx = threadIdx.x & 31, ty = threadIdx.x >> 5;
    #pragma unroll
    for (int r = 0; r < 4; ++r)
        ts[ty + r * 8][tx] = in[(size_t)(k0 + ty + r * 8) * Nd + n0 + tx];
    __syncthreads();
    #pragma unroll
    for (int r = 0; r < 4; ++r)
        o[(size_t)(n0 + ty + r * 8) * Kd + k0 + tx] = f2bf(ts[tx][ty + r * 8]);
}

/* ============ dual input projection (z=0 src, z=1 tgt) ============ */
__global__ __launch_bounds__(256) void input_proj2(
    const float* __restrict__ x0, const float* __restrict__ w0,
    const float* __restrict__ b0, const float* __restrict__ p0,
    float* __restrict__ o0_32, ushort* __restrict__ o0_b, int in0,
    const float* __restrict__ x1, const float* __restrict__ w1,
    const float* __restrict__ b1, const float* __restrict__ p1,
    float* __restrict__ o1_32, ushort* __restrict__ o1_b, int in1)
{
    const int z = blockIdx.y;
    const float* x = z ? x1 : x0;  const float* w = z ? w1 : w0;
    const float* bias = z ? b1 : b0; const float* pos = z ? p1 : p0;
    float* out32 = z ? o1_32 : o0_32; ushort* outb = z ? o1_b : o0_b;
    int in_size = z ? in1 : in0;
    int idx = blockIdx.x * 256 + threadIdx.x;
    int col = idx & (D_MODEL - 1);
    int row = idx >> 9;
    int l   = row & (SEQ - 1);
    const float* xr = x + (size_t)row * in_size;
    float acc = bias[col] + pos[(size_t)l * D_MODEL + col];
    for (int t = 0; t < in_size; ++t) acc += xr[t] * w[(size_t)t * D_MODEL + col];
    out32[idx] = acc;
    outb[idx]  = f2bf(acc);
}

/* ============ final projection ============ */
__global__ __launch_bounds__(256) void final_proj(
    const float* __restrict__ X, const float* __restrict__ W,
    const float* __restrict__ b, float* __restrict__ out)
{
    int idx = blockIdx.x * 256 + threadIdx.x;
    int row = idx >> 3, c = idx & 7;
    const float* xr = X + (size_t)row * D_MODEL;
    float acc = b[c];
    for (int t = 0; t < D_MODEL; ++t) acc += xr[t] * W[t * 8 + c];
    out[idx] = acc;
}

/* ============================ host orchestration ============================ */
extern "C" void kernel_launch(void* const* d_in, const int* in_sizes, int n_in,
                              void* d_out, int out_size, void* d_ws, size_t ws_size,
                              hipStream_t stream)
{
    const float* src         = (const float*)d_in[0];
    const float* tgt         = (const float*)d_in[1];
    const float* src_pos     = (const float*)d_in[2];
    const float* tgt_pos     = (const float*)d_in[3];
    const float* src_lin_w   = (const float*)d_in[4];
    const float* src_lin_b   = (const float*)d_in[5];
    const float* tgt_lin_w   = (const float*)d_in[6];
    const float* tgt_lin_b   = (const float*)d_in[7];
    const float* enc_wq      = (const float*)d_in[8];
    const float* enc_wk      = (const float*)d_in[9];
    const float* enc_wv      = (const float*)d_in[10];
    const float* enc_wo      = (const float*)d_in[11];
    const float* enc_ff1_w   = (const float*)d_in[12];
    const float* enc_ff1_b   = (const float*)d_in[13];
    const float* enc_ff2_w   = (const float*)d_in[14];
    const float* enc_ff2_b   = (const float*)d_in[15];
    const float* enc_ln1_g   = (const float*)d_in[16];
    const float* enc_ln1_b   = (const float*)d_in[17];
    const float* enc_ln2_g   = (const float*)d_in[18];
    const float* enc_ln2_b   = (const float*)d_in[19];
    const float* dec_sa_wq   = (const float*)d_in[20];
    const float* dec_sa_wk   = (const float*)d_in[21];
    const float* dec_sa_wv   = (const float*)d_in[22];
    const float* dec_sa_wo   = (const float*)d_in[23];
    const float* dec_ca_wq   = (const float*)d_in[24];
    const float* dec_ca_wk   = (const float*)d_in[25];
    const float* dec_ca_wv   = (const float*)d_in[26];
    const float* dec_ca_wo   = (const float*)d_in[27];
    const float* dec_ff1_w   = (const float*)d_in[28];
    const float* dec_ff1_b   = (const float*)d_in[29];
    const float* dec_ff2_w   = (const float*)d_in[30];
    const float* dec_ff2_b   = (const float*)d_in[31];
    const float* dec_ln1_g   = (const float*)d_in[32];
    const float* dec_ln1_b   = (const float*)d_in[33];
    const float* dec_ln2_g   = (const float*)d_in[34];
    const float* dec_ln2_b   = (const float*)d_in[35];
    const float* dec_ln3_g   = (const float*)d_in[36];
    const float* dec_ln3_b   = (const float*)d_in[37];
    const float* proj_w      = (const float*)d_in[38];
    const float* proj_b      = (const float*)d_in[39];

    /* ---- workspace carve ---- */
    char* p = (char*)d_ws;
    auto carve = [&](size_t bytes) { char* r = p; p += (bytes + 255) & ~(size_t)255; return r; };
    ushort* enc_xb = (ushort*)carve((size_t)ROWS * D_MODEL * 2);
    ushort* dec_xb = (ushort*)carve((size_t)ROWS * D_MODEL * 2);
    float*  enc_x32= (float*) carve((size_t)ROWS * D_MODEL * 4);
    float*  dec_x32= (float*) carve((size_t)ROWS * D_MODEL * 4);
    ushort* qkvb   = (ushort*)carve((size_t)ROWS * 1536 * 2);
    ushort* qb     = (ushort*)carve((size_t)ROWS * D_MODEL * 2);
    ushort* kvb    = (ushort*)carve((size_t)ROWS * 1024 * 2);
    ushort* ctxb   = (ushort*)carve((size_t)ROWS * D_MODEL * 2);
    ushort* attnb  = (ushort*)carve((size_t)ROWS * D_MODEL * 2);
    ushort* ffhb   = (ushort*)carve((size_t)ROWS * D_FF * 2);
    ushort* vt     = (ushort*)carve((size_t)64 * D_HEAD * SEQ * 2);
    ushort* wa     = (ushort*)carve((size_t)48 * 262144 * 2);
    ushort* wf     = (ushort*)carve((size_t)16 * 1048576 * 2);
    unsigned int* cnts = (unsigned int*)carve((size_t)20 * 32 * 4);

    const dim3 blk(256);

    /* counters must be zero every call (ws poisoned 0xAA) */
    hipMemsetAsync(cnts, 0, 20 * 32 * sizeof(unsigned int), stream);

    /* ---- weight repack (2 launches) ---- */
    {
        AttnPtrs A;
        for (int i = 0; i < 4; ++i) {
            const size_t o = (size_t)i * 262144;
            A.p[i * 3 + 0] = enc_wq + o;  A.p[i * 3 + 1] = enc_wk + o;  A.p[i * 3 + 2] = enc_wv + o;
            A.p[12 + i] = enc_wo + o;
            A.p[16 + i * 3 + 0] = dec_sa_wq + o; A.p[16 + i * 3 + 1] = dec_sa_wk + o;
            A.p[16 + i * 3 + 2] = dec_sa_wv + o;
            A.p[28 + i] = dec_sa_wo + o;
            A.p[32 + i * 2 + 0] = dec_ca_wk + o; A.p[32 + i * 2 + 1] = dec_ca_wv + o;
            A.p[40 + i] = dec_ca_wq + o;
            A.p[44 + i] = dec_ca_wo + o;
        }
        repack_attn<<<dim3(16, 16, 48), blk, 0, stream>>>(A, wa);
        FfPtrs F;
        for (int i = 0; i < 4; ++i) {
            F.p[0 + i]  = enc_ff1_w + (size_t)i * 1048576;
            F.p[4 + i]  = dec_ff1_w + (size_t)i * 1048576;
            F.p[8 + i]  = enc_ff2_w + (size_t)i * 1048576;
            F.p[12 + i] = dec_ff2_w + (size_t)i * 1048576;
        }
        repack_ff<<<dim3(1024, 16), blk, 0, stream>>>(F, wf);
    }

    auto mkd = [&](const ushort* A, int lda, const ushort* Bt, int ldb,
                   ushort* C, int ldc, int N, int K,
                   const float* bias, int relu, ushort* VT, int vcol0) {
        GDesc d; d.A = A; d.lda = lda; d.Bt = Bt; d.ldb = ldb;
        d.C = C; d.ldc = ldc; d.N = N; d.K = K;
        d.bias = bias; d.relu = relu; d.VT = VT; d.vcol0 = vcol0;
        d.resid32 = nullptr; d.gamma = nullptr; d.beta = nullptr;
        d.out32 = nullptr; d.outb = nullptr; d.cnt = nullptr; d.nblk = 0;
        return d;
    };
    auto g128 = [&](const GDesc& d) {
        gemm_one<128><<<dim3(d.N / 128, ROWS / 128), blk, 0, stream>>>(d);
    };
    auto gfuse = [&](const ushort* A, int lda, const ushort* Bt,
                     int K, const float* bias,
                     const float* resid, const float* gamma, const float* beta,
                     float* o32, ushort* ob, int inst) {
        GDesc d = mkd(A, lda, Bt, K, attnb, 512, 512, K, bias, 0, nullptr, 0);
        /* fix fields (mkd signature reuse) */
        d.Bt = Bt; d.ldb = K; d.C = attnb; d.ldc = 512; d.N = 512; d.K = K;
        d.resid32 = resid; d.gamma = gamma; d.beta = beta;
        d.out32 = o32; d.outb = ob; d.cnt = cnts + inst * 32; d.nblk = 8;
        gemm_fused<<<dim3(8, 32), blk, 0, stream>>>(d);
    };

    /* input projections (1 launch) */
    input_proj2<<<dim3(ROWS * D_MODEL / 256, 2), blk, 0, stream>>>(
        src, src_lin_w, src_lin_b, src_pos, enc_x32, enc_xb, 16,
        tgt, tgt_lin_w, tgt_lin_b, tgt_pos, dec_x32, dec_xb, 8);

    /* ===================== encoder ===================== */
    for (int i = 0; i < 4; ++i) {
        g128(mkd(enc_xb, 512, wa + (size_t)(i * 3) * 262144, 512, qkvb, 1536,
                 1536, 512, nullptr, 0, vt, 1024));
        flash_attn<<<dim3(8, 64), blk, 0, stream>>>(qkvb, 1536, qkvb + 512, 1536, vt,
                                                    ctxb, D_MODEL, SEQ);
        gfuse(ctxb, 512, wa + (size_t)(12 + i) * 262144, 512, nullptr,
              enc_x32, enc_ln1_g + i * 512, enc_ln1_b + i * 512,
              enc_x32, enc_xb, i * 2);
        g128(mkd(enc_xb, 512, wf + (size_t)i * 1048576, 512, ffhb, 2048,
                 2048, 512, enc_ff1_b + i * 2048, 1, nullptr, 0));
        gfuse(ffhb, 2048, wf + (size_t)(8 + i) * 1048576, 2048, enc_ff2_b + i * 512,
              enc_x32, enc_ln2_g + i * 512, enc_ln2_b + i * 512,
              enc_x32, enc_xb, i * 2 + 1);
    }

    /* ===================== decoder ===================== */
    for (int i = 0; i < 4; ++i) {
        /* masked self-attention */
        g128(mkd(dec_xb, 512, wa + (size_t)(16 + i * 3) * 262144, 512, qkvb, 1536,
                 1536, 512, nullptr, 0, vt, 1024));
        flash_attn<<<dim3(8, 64), blk, 0, stream>>>(qkvb, 1536, qkvb + 512, 1536, vt,
                                                    ctxb, D_MODEL, KLEN_MASKED);
        gfuse(ctxb, 512, wa + (size_t)(28 + i) * 262144, 512, nullptr,
              dec_x32, dec_ln1_g + i * 512, dec_ln1_b + i * 512,
              dec_x32, dec_xb, 8 + i * 3);
        /* cross-attention: q-proj (dec_x) and kv-proj (enc_x) in ONE launch */
        {
            GDesc dq = mkd(dec_xb, 512, wa + (size_t)(40 + i) * 262144, 512, qb, 512,
                           512, 512, nullptr, 0, nullptr, 0);
            GDesc dkv = mkd(enc_xb, 512, wa + (size_t)(32 + i * 2) * 262144, 512, kvb, 1024,
                            1024, 512, nullptr, 0, vt, 512);
            gemm_two<<<dim3(8, ROWS / 128, 2), blk, 0, stream>>>(dq, dkv);
        }
        flash_attn<<<dim3(8, 64), blk, 0, stream>>>(qb, 512, kvb, 1024, vt,
                                                    ctxb, D_MODEL, SEQ);
        gfuse(ctxb, 512, wa + (size_t)(44 + i) * 262144, 512, nullptr,
              dec_x32, dec_ln2_g + i * 512, dec_ln2_b + i * 512,
              dec_x32, dec_xb, 8 + i * 3 + 1);
        /* feed-forward */
        g128(mkd(dec_xb, 512, wf + (size_t)(4 + i) * 1048576, 512, ffhb, 2048,
                 2048, 512, dec_ff1_b + i * 2048, 1, nullptr, 0));
        gfuse(ffhb, 2048, wf + (size_t)(12 + i) * 1048576, 2048, dec_ff2_b + i * 512,
              dec_x32, dec_ln3_g + i * 512, dec_ln3_b + i * 512,
              dec_x32, dec_xb, 8 + i * 3 + 2);
    }

    /* final projection */
    final_proj<<<ROWS * 8 / 256, blk, 0, stream>>>(dec_x32, proj_w, proj_b, (float*)d_out);
}

// Round 7
// 1689.960 us; speedup vs baseline: 1.4717x; 1.4717x over previous
//
#include <hip/hip_runtime.h>
#include <hip/hip_bf16.h>
#include <math.h>

#define D_MODEL 512
#define N_HEADS 8
#define D_HEAD  64
#define D_FF    2048
#define SEQ     512
#define BATCH   8
#define ROWS    (BATCH * SEQ)          /* 4096 */
#define PRED_LEN 96
#define KLEN_MASKED (SEQ - PRED_LEN)   /* 416 */
#define LN_EPS  1e-5f

typedef float  f32x4 __attribute__((ext_vector_type(4)));
typedef short  s16x8 __attribute__((ext_vector_type(8)));

__device__ __forceinline__ float bf2f(ushort u) {
    union { unsigned int i; float f; } c; c.i = ((unsigned int)u) << 16; return c.f;
}
__device__ __forceinline__ ushort f2bf(float v) {
    __hip_bfloat16 h = __float2bfloat16(v);
    return *(ushort*)&h;
}
__device__ __forceinline__ void gl_lds16(const void* g, void* lds) {
    __builtin_amdgcn_global_load_lds(
        (const __attribute__((address_space(1))) unsigned int*)g,
        (__attribute__((address_space(3))) unsigned int*)lds, 16, 0, 0);
}

/* ==================== consumer GEMM (optional folded LN on A) ===============
 * C = [LN-corrected] A @ Bt^T + bias (opt relu).  BM=128, BK=32, 4 waves 2x2.
 * If statsA: out = rs*P - rs*mu*sgamma[col] + cbeta[col] + bias (exact fold of
 * y=(t-mu)*rs*g+b through the GEMM; sgamma/cbeta precomputed at repack).
 * VT-epilogue (validated R4): blocks with n0>=vcol0 write per-head transposed V.
 */
struct GDesc {
    const ushort* A; int lda;
    const ushort* Bt; int ldb;
    ushort* C; int ldc;
    int N; int K;
    const float* bias; int relu;
    ushort* VT; int vcol0;
    const float2* statsA;   /* [8][4096] (sum, sumsq) partials for A rows; null = raw */
    const float* cs;        /* per-matrix colsums: [z][0..csN)=sgamma, [z][csN..2csN)=cbeta */
    int csShift; int csMask;/* z = col >> csShift; off = col & csMask; csN = csMask+1 */
};

template<int BN>
__device__ __forceinline__ void cons_body(const GDesc& d)
{
    constexpr int NW = BN / 32;
    __shared__ __attribute__((aligned(16))) ushort As[128 * 32];
    __shared__ __attribute__((aligned(16))) ushort Bs[BN * 32];
    __shared__ float2 mrs[128];
    const int tid = threadIdx.x;
    const int w = tid >> 6, lane = tid & 63;
    const int l16 = lane & 15, quad = lane >> 4;
    const int m0 = blockIdx.y * 128, n0 = blockIdx.x * BN;
    if (d.statsA != nullptr && tid < 128) {
        float S = 0.f, Q = 0.f;
        #pragma unroll
        for (int j = 0; j < 8; ++j) {
            float2 pp = d.statsA[j * 4096 + m0 + tid];
            S += pp.x; Q += pp.y;
        }
        float mu = S * (1.f / 512.f);
        float var = Q * (1.f / 512.f) - mu * mu;
        mrs[tid] = make_float2(mu, rsqrtf(var + LN_EPS));
    }
    const ushort* Ab = d.A + (size_t)m0 * d.lda;
    const ushort* Bb = d.Bt + (size_t)n0 * d.ldb;
    const int wm = (w >> 1) * 64, wn = (w & 1) * (BN / 2);
    const int K = d.K;

    f32x4 acc[4][NW];
    #pragma unroll
    for (int i = 0; i < 4; ++i)
        #pragma unroll
        for (int j = 0; j < NW; ++j) acc[i][j] = (f32x4)0.f;

    for (int k0 = 0; k0 < K; k0 += 32) {
        #pragma unroll
        for (int t = 0; t < 2; ++t) {
            int c = (t * 4 + w) * 64 + lane;
            gl_lds16(Ab + (size_t)(c >> 2) * d.lda + k0 + (c & 3) * 8,
                     (void*)(As + (size_t)(t * 4 + w) * 512));
        }
        #pragma unroll
        for (int t = 0; t < BN / 64; ++t) {
            int c = (t * 4 + w) * 64 + lane;
            gl_lds16(Bb + (size_t)(c >> 2) * d.ldb + k0 + (c & 3) * 8,
                     (void*)(Bs + (size_t)(t * 4 + w) * 512));
        }
        __syncthreads();
        s16x8 af[4];
        #pragma unroll
        for (int i = 0; i < 4; ++i)
            af[i] = *(const s16x8*)(As + (size_t)(wm + i * 16 + l16) * 32 + quad * 8);
        #pragma unroll
        for (int j = 0; j < NW; ++j) {
            s16x8 bfr = *(const s16x8*)(Bs + (size_t)(wn + j * 16 + l16) * 32 + quad * 8);
            #pragma unroll
            for (int i = 0; i < 4; ++i)
                acc[i][j] = __builtin_amdgcn_mfma_f32_16x16x32_bf16(af[i], bfr, acc[i][j], 0, 0, 0);
        }
        __syncthreads();
    }
    const bool isv = (d.VT != nullptr) && (n0 >= d.vcol0);
    #pragma unroll
    for (int i = 0; i < 4; ++i) {
        #pragma unroll
        for (int j = 0; j < NW; ++j) {
            int col = n0 + wn + j * 16 + l16;
            float sg = 0.f, cb = 0.f;
            if (d.statsA) {
                int zi = col >> d.csShift;
                int off = col & d.csMask;
                const float* c0 = d.cs + (size_t)zi * 2 * (d.csMask + 1);
                sg = c0[off];
                cb = c0[d.csMask + 1 + off];
            }
            float bv = d.bias ? d.bias[col] : 0.f;
            float vv[4];
            #pragma unroll
            for (int r = 0; r < 4; ++r) {
                float v = acc[i][j][r];
                if (d.statsA) {
                    float2 m = mrs[wm + i * 16 + quad * 4 + r];
                    v = m.y * v - m.y * m.x * sg + cb;
                }
                v += bv;
                if (d.relu) v = fmaxf(v, 0.f);
                vv[r] = v;
            }
            if (isv) {
                int mrow = m0 + wm + i * 16 + quad * 4;
                int b = mrow >> 9, pbase = mrow & 511;
                int cv = col - d.vcol0;
                int h = cv >> 6, dd = cv & 63;
                union { ushort u[4]; uint2 v2; } pk;
                #pragma unroll
                for (int r = 0; r < 4; ++r) pk.u[r] = f2bf(vv[r]);
                *(uint2*)(d.VT + ((size_t)((b * 8 + h) * 64 + dd) * 512 + pbase)) = pk.v2;
            } else {
                #pragma unroll
                for (int r = 0; r < 4; ++r)
                    d.C[(size_t)(m0 + wm + i * 16 + quad * 4 + r) * d.ldc + col] = f2bf(vv[r]);
            }
        }
    }
}

template<int BN>
__global__ __launch_bounds__(256) void gemm_one(GDesc d)
{
    if ((int)(blockIdx.x * BN) < d.N) cons_body<BN>(d);
}

__global__ __launch_bounds__(256) void gemm_two(GDesc d0, GDesc d1)
{
    const GDesc& d = blockIdx.z ? d1 : d0;
    if ((int)(blockIdx.x * 128) < d.N) cons_body<128>(d);
}

/* ==================== producer GEMM: t = A@Bt^T + bias + y_prev =============
 * Writes fp32+bf16 carrier t and per-column-slice row stats partials.
 * y_prev reconstructed from prev carrier (+stats+gamma/beta) or raw if statsP=0.
 * N=512 fixed, BN=64, grid (8, 32).
 */
struct PDesc {
    const ushort* A; int lda;
    const ushort* Bt; int ldb; int K;
    const float* bias;
    const float* prev32;
    const float2* statsP;
    const float* gprev; const float* bprev;
    float* t32; ushort* tb;
    float2* statsOut;           /* [8][4096] */
};

__global__ __launch_bounds__(256) void gemm_prod(PDesc d)
{
    __shared__ __attribute__((aligned(16))) ushort As[128 * 32];
    __shared__ __attribute__((aligned(16))) ushort Bs[64 * 32];
    __shared__ float2 mrsP[128];
    __shared__ float sS[2][128], sQ[2][128];
    const int tid = threadIdx.x;
    const int w = tid >> 6, lane = tid & 63;
    const int l16 = lane & 15, quad = lane >> 4;
    const int m0 = blockIdx.y * 128, n0 = blockIdx.x * 64;
    if (d.statsP != nullptr && tid < 128) {
        float S = 0.f, Q = 0.f;
        #pragma unroll
        for (int j = 0; j < 8; ++j) {
            float2 pp = d.statsP[j * 4096 + m0 + tid];
            S += pp.x; Q += pp.y;
        }
        float mu = S * (1.f / 512.f);
        float var = Q * (1.f / 512.f) - mu * mu;
        mrsP[tid] = make_float2(mu, rsqrtf(var + LN_EPS));
    }
    const ushort* Ab = d.A + (size_t)m0 * d.lda;
    const ushort* Bb = d.Bt + (size_t)n0 * d.ldb;
    const int wm = (w >> 1) * 64, wn = (w & 1) * 32;
    const int K = d.K;

    f32x4 acc[4][2];
    #pragma unroll
    for (int i = 0; i < 4; ++i)
        #pragma unroll
        for (int j = 0; j < 2; ++j) acc[i][j] = (f32x4)0.f;

    for (int k0 = 0; k0 < K; k0 += 32) {
        #pragma unroll
        for (int t = 0; t < 2; ++t) {
            int c = (t * 4 + w) * 64 + lane;
            gl_lds16(Ab + (size_t)(c >> 2) * d.lda + k0 + (c & 3) * 8,
                     (void*)(As + (size_t)(t * 4 + w) * 512));
        }
        {
            int c = w * 64 + lane;
            gl_lds16(Bb + (size_t)(c >> 2) * d.ldb + k0 + (c & 3) * 8,
                     (void*)(Bs + (size_t)w * 512));
        }
        __syncthreads();
        s16x8 af[4];
        #pragma unroll
        for (int i = 0; i < 4; ++i)
            af[i] = *(const s16x8*)(As + (size_t)(wm + i * 16 + l16) * 32 + quad * 8);
        #pragma unroll
        for (int j = 0; j < 2; ++j) {
            s16x8 bfr = *(const s16x8*)(Bs + (size_t)(wn + j * 16 + l16) * 32 + quad * 8);
            #pragma unroll
            for (int i = 0; i < 4; ++i)
                acc[i][j] = __builtin_amdgcn_mfma_f32_16x16x32_bf16(af[i], bfr, acc[i][j], 0, 0, 0);
        }
        __syncthreads();
    }

    int cols[2]; float bvv[2], gpv[2] = {0.f, 0.f}, bpv[2] = {0.f, 0.f};
    #pragma unroll
    for (int j = 0; j < 2; ++j) {
        cols[j] = n0 + wn + j * 16 + l16;
        bvv[j] = d.bias ? d.bias[cols[j]] : 0.f;
        if (d.statsP) { gpv[j] = d.gprev[cols[j]]; bpv[j] = d.bprev[cols[j]]; }
    }
    #pragma unroll
    for (int i = 0; i < 4; ++i) {
        #pragma unroll
        for (int r = 0; r < 4; ++r) {
            int rl = wm + i * 16 + quad * 4 + r;
            size_t grow = (size_t)(m0 + rl) * 512;
            float s = 0.f, q = 0.f;
            #pragma unroll
            for (int j = 0; j < 2; ++j) {
                float v = acc[i][j][r] + bvv[j];
                float pv = d.prev32[grow + cols[j]];
                float yp;
                if (d.statsP) {
                    float2 mp = mrsP[rl];
                    yp = (pv - mp.x) * mp.y * gpv[j] + bpv[j];
                } else yp = pv;
                float t = v + yp;
                d.t32[grow + cols[j]] = t;
                d.tb[grow + cols[j]] = f2bf(t);
                s += t; q += t * t;
            }
            s += __shfl_xor(s, 1); s += __shfl_xor(s, 2);
            s += __shfl_xor(s, 4); s += __shfl_xor(s, 8);
            q += __shfl_xor(q, 1); q += __shfl_xor(q, 2);
            q += __shfl_xor(q, 4); q += __shfl_xor(q, 8);
            if (l16 == 0) { sS[w & 1][rl] = s; sQ[w & 1][rl] = q; }
        }
    }
    __syncthreads();
    if (tid < 128)
        d.statsOut[blockIdx.x * 4096 + m0 + tid] =
            make_float2(sS[0][tid] + sS[1][tid], sQ[0][tid] + sQ[1][tid]);
}

/* ==================== flash attention (unchanged from R5) =================== */
__global__ __launch_bounds__(256) void flash_attn(
    const ushort* __restrict__ Q, int ldq,
    const ushort* __restrict__ K, int ldk,
    const ushort* __restrict__ Vt,
    ushort* __restrict__ O, int ldo, int klen)
{
    __shared__ __attribute__((aligned(16))) ushort KVs[8192];
    __shared__ __attribute__((aligned(16))) ushort Es[4][2048];
    const int tid = threadIdx.x, w = tid >> 6, lane = tid & 63;
    const int l16 = lane & 15, quad = lane >> 4;
    const int bh = blockIdx.y, b = bh >> 3, h = bh & 7;
    const int q0 = blockIdx.x * 64;

    const ushort* Qb = Q + (size_t)(b * SEQ) * ldq + h * D_HEAD;
    const ushort* Kb = K + (size_t)(b * SEQ) * ldk + h * D_HEAD;

    s16x8 af0, af1;
    {
        const ushort* qr = Qb + (size_t)(q0 + w * 16 + l16) * ldq + quad * 8;
        af0 = *(const s16x8*)(qr);
        af1 = *(const s16x8*)(qr + 32);
    }

    f32x4 sc[32];

    #pragma unroll
    for (int kc = 0; kc < 4; ++kc) {
        #pragma unroll
        for (int it = 0; it < 4; ++it) {
            int cc = (it * 4 + w) * 64 + lane;
            int row = cc >> 3;
            int dch = (cc & 7) ^ (row & 7);
            gl_lds16(Kb + (size_t)(kc * 128 + row) * ldk + dch * 8,
                     (void*)(KVs + (size_t)(it * 4 + w) * 512));
        }
        __syncthreads();
        #pragma unroll
        for (int kt = 0; kt < 8; ++kt) {
            int r0 = kt * 16 + l16;
            s16x8 b0 = *(const s16x8*)(KVs + r0 * 64 + ((quad)     ^ (r0 & 7)) * 8);
            s16x8 b1 = *(const s16x8*)(KVs + r0 * 64 + ((4 + quad) ^ (r0 & 7)) * 8);
            f32x4 a = __builtin_amdgcn_mfma_f32_16x16x32_bf16(af0, b0, (f32x4)0.f, 0, 0, 0);
            sc[kc * 8 + kt] = __builtin_amdgcn_mfma_f32_16x16x32_bf16(af1, b1, a, 0, 0, 0);
        }
        __syncthreads();
    }

    float inv[4];
    #pragma unroll
    for (int r = 0; r < 4; ++r) {
        float m = -1e30f;
        #pragma unroll
        for (int j = 0; j < 32; ++j) {
            bool valid = (j * 16 + l16) < klen;
            m = valid ? fmaxf(m, sc[j][r]) : m;
        }
        m = fmaxf(m, __shfl_xor(m, 1));
        m = fmaxf(m, __shfl_xor(m, 2));
        m = fmaxf(m, __shfl_xor(m, 4));
        m = fmaxf(m, __shfl_xor(m, 8));
        float ssum = 0.f;
        #pragma unroll
        for (int j = 0; j < 32; ++j) {
            bool valid = (j * 16 + l16) < klen;
            float e = valid ? __expf((sc[j][r] - m) * 0.125f) : 0.f;
            sc[j][r] = e;
            ssum += e;
        }
        ssum += __shfl_xor(ssum, 1);
        ssum += __shfl_xor(ssum, 2);
        ssum += __shfl_xor(ssum, 4);
        ssum += __shfl_xor(ssum, 8);
        inv[r] = 1.f / ssum;
    }

    f32x4 oacc[4];
    #pragma unroll
    for (int jd = 0; jd < 4; ++jd) oacc[jd] = (f32x4)0.f;
    const ushort* Vb = Vt + (size_t)bh * (D_HEAD * SEQ);
    #pragma unroll
    for (int kc = 0; kc < 4; ++kc) {
        #pragma unroll
        for (int it = 0; it < 4; ++it) {
            int cc = (it * 4 + w) * 64 + lane;
            int dd = cc >> 4;
            int kch = (cc & 15) ^ (dd & 15);
            gl_lds16(Vb + (size_t)dd * SEQ + kc * 128 + kch * 8,
                     (void*)(KVs + (size_t)(it * 4 + w) * 512));
        }
        #pragma unroll
        for (int j = 0; j < 8; ++j) {
            int lcj = j * 2 + (l16 >> 3);
            #pragma unroll
            for (int r = 0; r < 4; ++r) {
                int m = quad * 4 + r;
                Es[w][m * 128 + (lcj ^ m) * 8 + (l16 & 7)] = f2bf(sc[kc * 8 + j][r]);
            }
        }
        __syncthreads();
        #pragma unroll
        for (int ks = 0; ks < 4; ++ks) {
            int lc = ks * 4 + quad;
            s16x8 ea = *(const s16x8*)(&Es[w][l16 * 128 + (lc ^ l16) * 8]);
            #pragma unroll
            for (int jd = 0; jd < 4; ++jd) {
                int row = jd * 16 + l16;
                s16x8 vb = *(const s16x8*)(KVs + row * 128 + (lc ^ l16) * 8);
                oacc[jd] = __builtin_amdgcn_mfma_f32_16x16x32_bf16(ea, vb, oacc[jd], 0, 0, 0);
            }
        }
        __syncthreads();
    }

    ushort* Ob = O + (size_t)(b * SEQ) * ldo + h * D_HEAD;
    #pragma unroll
    for (int jd = 0; jd < 4; ++jd)
        #pragma unroll
        for (int r = 0; r < 4; ++r)
            Ob[(size_t)(q0 + w * 16 + quad * 4 + r) * ldo + jd * 16 + l16] =
                f2bf(oacc[jd][r] * inv[r]);
}

/* ==================== weight repacks (+gamma scaling, +colsums) ============= */
struct AttnCtl { const float* w[48]; const float* g[48]; const float* b[48]; };
struct FfCtl   { const float* w[16]; const float* g[16]; const float* b[16]; };

__global__ __launch_bounds__(256) void repack_attn(AttnCtl L, ushort* __restrict__ out,
                                                   float* __restrict__ cs)
{
    int z = blockIdx.z;
    const float* in = L.w[z];
    const float* gz = L.g[z];
    const float* bz = L.b[z];
    ushort* o = out + (size_t)z * 262144;
    __shared__ float t[32][33];
    int n0 = blockIdx.x * 32, k0 = blockIdx.y * 32;
    int tx = threadIdx.x & 31, ty = threadIdx.x >> 5;
    #pragma unroll
    for (int r = 0; r < 4; ++r)
        t[ty + r * 8][tx] = in[(size_t)(k0 + ty + r * 8) * 512 + n0 + tx];
    __syncthreads();
    #pragma unroll
    for (int r = 0; r < 4; ++r) {
        int n = n0 + ty + r * 8, k = k0 + tx;
        float wv = t[tx][ty + r * 8];
        if (gz) {
            ushort wb = f2bf(wv * gz[k]);
            o[(size_t)n * 512 + k] = wb;
            float sgl = bf2f(wb);
            float cbl = wv * bz[k];
            #pragma unroll
            for (int m = 1; m < 32; m <<= 1) {
                sgl += __shfl_xor(sgl, m);
                cbl += __shfl_xor(cbl, m);
            }
            if (tx == 0) {
                atomicAdd(&cs[(size_t)z * 1024 + n], sgl);
                atomicAdd(&cs[(size_t)z * 1024 + 512 + n], cbl);
            }
        } else {
            o[(size_t)n * 512 + k] = f2bf(wv);
        }
    }
}

__global__ __launch_bounds__(256) void repack_ff(FfCtl L, ushort* __restrict__ out,
                                                 float* __restrict__ cs)
{
    int z = blockIdx.y;
    int Kd = (z < 8) ? 512 : 2048, Nd = (z < 8) ? 2048 : 512;
    const float* in = L.w[z];
    const float* gz = L.g[z];
    const float* bz = L.b[z];
    ushort* o = out + (size_t)z * (512 * 2048);
    int tt = blockIdx.x;
    int tn = Nd / 32;
    int n0 = (tt % tn) * 32, k0 = (tt / tn) * 32;
    __shared__ float ts[32][33];
    int tx = threadIdx.x & 31, ty = threadIdx.x >> 5;
    #pragma unroll
    for (int r = 0; r < 4; ++r)
        ts[ty + r * 8][tx] = in[(size_t)(k0 + ty + r * 8) * Nd + n0 + tx];
    __syncthreads();
    #pragma unroll
    for (int r = 0; r < 4; ++r) {
        int n = n0 + ty + r * 8, k = k0 + tx;
        float wv = ts[tx][ty + r * 8];
        if (gz) {
            ushort wb = f2bf(wv * gz[k]);
            o[(size_t)n * Kd + k] = wb;
            float sgl = bf2f(wb);
            float cbl = wv * bz[k];
            #pragma unroll
            for (int m = 1; m < 32; m <<= 1) {
                sgl += __shfl_xor(sgl, m);
                cbl += __shfl_xor(cbl, m);
            }
            if (tx == 0) {
                atomicAdd(&cs[(size_t)z * 4096 + n], sgl);
                atomicAdd(&cs[(size_t)z * 4096 + 2048 + n], cbl);
            }
        } else {
            o[(size_t)n * Kd + k] = f2bf(wv);
        }
    }
}

/* ==================== dual input projection ==================== */
__global__ __launch_bounds__(256) void input_proj2(
    const float* __restrict__ x0, const float* __restrict__ w0,
    const float* __restrict__ b0, const float* __restrict__ p0,
    float* __restrict__ o0_32, ushort* __restrict__ o0_b, int in0,
    const float* __restrict__ x1, const float* __restrict__ w1,
    const float* __restrict__ b1, const float* __restrict__ p1,
    float* __restrict__ o1_32, ushort* __restrict__ o1_b, int in1)
{
    const int z = blockIdx.y;
    const float* x = z ? x1 : x0;  const float* w = z ? w1 : w0;
    const float* bias = z ? b1 : b0; const float* pos = z ? p1 : p0;
    float* out32 = z ? o1_32 : o0_32; ushort* outb = z ? o1_b : o0_b;
    int in_size = z ? in1 : in0;
    int idx = blockIdx.x * 256 + threadIdx.x;
    int col = idx & (D_MODEL - 1);
    int row = idx >> 9;
    int l   = row & (SEQ - 1);
    const float* xr = x + (size_t)row * in_size;
    float acc = bias[col] + pos[(size_t)l * D_MODEL + col];
    for (int t = 0; t < in_size; ++t) acc += xr[t] * w[(size_t)t * D_MODEL + col];
    out32[idx] = acc;
    outb[idx]  = f2bf(acc);
}

/* ==================== final projection with inline LN ==================== */
__global__ __launch_bounds__(256) void final_proj_ln(
    const float* __restrict__ t32, const float2* __restrict__ stats,
    const float* __restrict__ g, const float* __restrict__ b,
    const float* __restrict__ W, const float* __restrict__ pb,
    float* __restrict__ out)
{
    int idx = blockIdx.x * 256 + threadIdx.x;
    int row = idx >> 3, c = idx & 7;
    float S = 0.f, Q = 0.f;
    #pragma unroll
    for (int j = 0; j < 8; ++j) {
        float2 pp = stats[j * 4096 + row];
        S += pp.x; Q += pp.y;
    }
    float mu = S * (1.f / 512.f);
    float rs = rsqrtf(Q * (1.f / 512.f) - mu * mu + LN_EPS);
    const float* tr = t32 + (size_t)row * 512;
    float acc = pb[c];
    for (int k = 0; k < 512; ++k) {
        float y = (tr[k] - mu) * rs * g[k] + b[k];
        acc += y * W[k * 8 + c];
    }
    out[idx] = acc;
}

/* ============================ host orchestration ============================ */
extern "C" void kernel_launch(void* const* d_in, const int* in_sizes, int n_in,
                              void* d_out, int out_size, void* d_ws, size_t ws_size,
                              hipStream_t stream)
{
    const float* src         = (const float*)d_in[0];
    const float* tgt         = (const float*)d_in[1];
    const float* src_pos     = (const float*)d_in[2];
    const float* tgt_pos     = (const float*)d_in[3];
    const float* src_lin_w   = (const float*)d_in[4];
    const float* src_lin_b   = (const float*)d_in[5];
    const float* tgt_lin_w   = (const float*)d_in[6];
    const float* tgt_lin_b   = (const float*)d_in[7];
    const float* enc_wq      = (const float*)d_in[8];
    const float* enc_wk      = (const float*)d_in[9];
    const float* enc_wv      = (const float*)d_in[10];
    const float* enc_wo      = (const float*)d_in[11];
    const float* enc_ff1_w   = (const float*)d_in[12];
    const float* enc_ff1_b   = (const float*)d_in[13];
    const float* enc_ff2_w   = (const float*)d_in[14];
    const float* enc_ff2_b   = (const float*)d_in[15];
    const float* enc_ln1_g   = (const float*)d_in[16];
    const float* enc_ln1_b   = (const float*)d_in[17];
    const float* enc_ln2_g   = (const float*)d_in[18];
    const float* enc_ln2_b   = (const float*)d_in[19];
    const float* dec_sa_wq   = (const float*)d_in[20];
    const float* dec_sa_wk   = (const float*)d_in[21];
    const float* dec_sa_wv   = (const float*)d_in[22];
    const float* dec_sa_wo   = (const float*)d_in[23];
    const float* dec_ca_wq   = (const float*)d_in[24];
    const float* dec_ca_wk   = (const float*)d_in[25];
    const float* dec_ca_wv   = (const float*)d_in[26];
    const float* dec_ca_wo   = (const float*)d_in[27];
    const float* dec_ff1_w   = (const float*)d_in[28];
    const float* dec_ff1_b   = (const float*)d_in[29];
    const float* dec_ff2_w   = (const float*)d_in[30];
    const float* dec_ff2_b   = (const float*)d_in[31];
    const float* dec_ln1_g   = (const float*)d_in[32];
    const float* dec_ln1_b   = (const float*)d_in[33];
    const float* dec_ln2_g   = (const float*)d_in[34];
    const float* dec_ln2_b   = (const float*)d_in[35];
    const float* dec_ln3_g   = (const float*)d_in[36];
    const float* dec_ln3_b   = (const float*)d_in[37];
    const float* proj_w      = (const float*)d_in[38];
    const float* proj_b      = (const float*)d_in[39];

    /* ---- workspace carve ---- */
    char* p = (char*)d_ws;
    auto carve = [&](size_t bytes) { char* r = p; p += (bytes + 255) & ~(size_t)255; return r; };
    const size_t C32 = (size_t)ROWS * 512 * 4, CB = (size_t)ROWS * 512 * 2;
    const size_t ST  = (size_t)8 * 4096 * sizeof(float2);
    float*  enc0_32 = (float*) carve(C32);  ushort* enc0_b = (ushort*)carve(CB);
    float*  dec0_32 = (float*) carve(C32);  ushort* dec0_b = (ushort*)carve(CB);
    float*  T1_32   = (float*) carve(C32);  ushort* T1_b   = (ushort*)carve(CB);
    float2* S_T1    = (float2*)carve(ST);
    float*  T2_32[2]; ushort* T2_b[2]; float2* S_T2[2];
    for (int i = 0; i < 2; ++i) {
        T2_32[i] = (float*)carve(C32); T2_b[i] = (ushort*)carve(CB);
        S_T2[i] = (float2*)carve(ST);
    }
    float*  U1_32   = (float*) carve(C32);  ushort* U1_b   = (ushort*)carve(CB);
    float2* S_U1    = (float2*)carve(ST);
    float*  U2_32   = (float*) carve(C32);  ushort* U2_b   = (ushort*)carve(CB);
    float2* S_U2    = (float2*)carve(ST);
    float*  T3_32[2]; ushort* T3_b[2]; float2* S_T3[2];
    for (int i = 0; i < 2; ++i) {
        T3_32[i] = (float*)carve(C32); T3_b[i] = (ushort*)carve(CB);
        S_T3[i] = (float2*)carve(ST);
    }
    ushort* qkvb = (ushort*)carve((size_t)ROWS * 1536 * 2);
    ushort* qb   = (ushort*)carve((size_t)ROWS * 512 * 2);
    ushort* kvb  = (ushort*)carve((size_t)ROWS * 1024 * 2);
    ushort* ctxb = (ushort*)carve((size_t)ROWS * 512 * 2);
    ushort* ffhb = (ushort*)carve((size_t)ROWS * D_FF * 2);
    ushort* vt   = (ushort*)carve((size_t)64 * D_HEAD * SEQ * 2);
    ushort* wa   = (ushort*)carve((size_t)48 * 262144 * 2);
    ushort* wf   = (ushort*)carve((size_t)16 * 1048576 * 2);
    float*  csA  = (float*) carve((size_t)(48 * 1024 + 16 * 4096) * 4);
    float*  csF  = csA + 48 * 1024;

    const dim3 blk(256);

    /* zero colsum accumulators (atomics target) */
    hipMemsetAsync(csA, 0, (size_t)(48 * 1024 + 16 * 4096) * 4, stream);

    /* ---- weight repack (2 launches) ---- */
    {
        AttnCtl A;
        for (int i = 0; i < 4; ++i) {
            const size_t o = (size_t)i * 262144;
            const float* g_qkv = (i == 0) ? nullptr : enc_ln2_g + (i - 1) * 512;
            const float* b_qkv = (i == 0) ? nullptr : enc_ln2_b + (i - 1) * 512;
            A.w[i * 3 + 0] = enc_wq + o;  A.g[i * 3 + 0] = g_qkv; A.b[i * 3 + 0] = b_qkv;
            A.w[i * 3 + 1] = enc_wk + o;  A.g[i * 3 + 1] = g_qkv; A.b[i * 3 + 1] = b_qkv;
            A.w[i * 3 + 2] = enc_wv + o;  A.g[i * 3 + 2] = g_qkv; A.b[i * 3 + 2] = b_qkv;
            A.w[12 + i] = enc_wo + o;     A.g[12 + i] = nullptr;  A.b[12 + i] = nullptr;
            const float* g_sa = (i == 0) ? nullptr : dec_ln3_g + (i - 1) * 512;
            const float* b_sa = (i == 0) ? nullptr : dec_ln3_b + (i - 1) * 512;
            A.w[16 + i * 3 + 0] = dec_sa_wq + o; A.g[16 + i * 3 + 0] = g_sa; A.b[16 + i * 3 + 0] = b_sa;
            A.w[16 + i * 3 + 1] = dec_sa_wk + o; A.g[16 + i * 3 + 1] = g_sa; A.b[16 + i * 3 + 1] = b_sa;
            A.w[16 + i * 3 + 2] = dec_sa_wv + o; A.g[16 + i * 3 + 2] = g_sa; A.b[16 + i * 3 + 2] = b_sa;
            A.w[28 + i] = dec_sa_wo + o;  A.g[28 + i] = nullptr;  A.b[28 + i] = nullptr;
            A.w[32 + i * 2 + 0] = dec_ca_wk + o; A.g[32 + i * 2 + 0] = enc_ln2_g + 3 * 512;
            A.b[32 + i * 2 + 0] = enc_ln2_b + 3 * 512;
            A.w[32 + i * 2 + 1] = dec_ca_wv + o; A.g[32 + i * 2 + 1] = enc_ln2_g + 3 * 512;
            A.b[32 + i * 2 + 1] = enc_ln2_b + 3 * 512;
            A.w[40 + i] = dec_ca_wq + o;  A.g[40 + i] = dec_ln1_g + i * 512;
            A.b[40 + i] = dec_ln1_b + i * 512;
            A.w[44 + i] = dec_ca_wo + o;  A.g[44 + i] = nullptr;  A.b[44 + i] = nullptr;
        }
        repack_attn<<<dim3(16, 16, 48), blk, 0, stream>>>(A, wa, csA);
        FfCtl F;
        for (int i = 0; i < 4; ++i) {
            F.w[0 + i]  = enc_ff1_w + (size_t)i * 1048576;
            F.g[0 + i]  = enc_ln1_g + i * 512;  F.b[0 + i] = enc_ln1_b + i * 512;
            F.w[4 + i]  = dec_ff1_w + (size_t)i * 1048576;
            F.g[4 + i]  = dec_ln2_g + i * 512;  F.b[4 + i] = dec_ln2_b + i * 512;
            F.w[8 + i]  = enc_ff2_w + (size_t)i * 1048576;
            F.g[8 + i]  = nullptr;              F.b[8 + i] = nullptr;
            F.w[12 + i] = dec_ff2_w + (size_t)i * 1048576;
            F.g[12 + i] = nullptr;              F.b[12 + i] = nullptr;
        }
        repack_ff<<<dim3(1024, 16), blk, 0, stream>>>(F, wf, csF);
    }

    auto mkd = [&](const ushort* A, int lda, const ushort* Bt, int ldb,
                   ushort* C, int ldc, int N, int K, const float* bias, int relu,
                   ushort* VT, int vcol0, const float2* statsA,
                   const float* cs, int csShift, int csMask) {
        GDesc d; d.A = A; d.lda = lda; d.Bt = Bt; d.ldb = ldb;
        d.C = C; d.ldc = ldc; d.N = N; d.K = K;
        d.bias = bias; d.relu = relu; d.VT = VT; d.vcol0 = vcol0;
        d.statsA = statsA; d.cs = cs; d.csShift = csShift; d.csMask = csMask;
        return d;
    };
    auto g128 = [&](const GDesc& d) {
        gemm_one<128><<<dim3(d.N / 128, ROWS / 128), blk, 0, stream>>>(d);
    };
    auto prod = [&](const ushort* A, int lda, const ushort* Bt, int K,
                    const float* bias, const float* prev32, const float2* statsP,
                    const float* gprev, const float* bprev,
                    float* t32, ushort* tb, float2* statsOut) {
        PDesc d; d.A = A; d.lda = lda; d.Bt = Bt; d.ldb = K; d.K = K;
        d.bias = bias; d.prev32 = prev32; d.statsP = statsP;
        d.gprev = gprev; d.bprev = bprev;
        d.t32 = t32; d.tb = tb; d.statsOut = statsOut;
        gemm_prod<<<dim3(8, 32), blk, 0, stream>>>(d);
    };

    /* input projections (raw carriers, no LN) */
    input_proj2<<<dim3(ROWS * 512 / 256, 2), blk, 0, stream>>>(
        src, src_lin_w, src_lin_b, src_pos, enc0_32, enc0_b, 16,
        tgt, tgt_lin_w, tgt_lin_b, tgt_pos, dec0_32, dec0_b, 8);

    /* ===================== encoder ===================== */
    for (int i = 0; i < 4; ++i) {
        const ushort* xa = i ? T2_b[(i - 1) & 1] : enc0_b;
        const float2* xs = i ? S_T2[(i - 1) & 1] : nullptr;
        const float*  xp32 = i ? T2_32[(i - 1) & 1] : enc0_32;
        const float*  xg = i ? enc_ln2_g + (i - 1) * 512 : nullptr;
        const float*  xb = i ? enc_ln2_b + (i - 1) * 512 : nullptr;
        /* QKV */
        g128(mkd(xa, 512, wa + (size_t)(i * 3) * 262144, 512, qkvb, 1536,
                 1536, 512, nullptr, 0, vt, 1024, xs, csA + (size_t)(i * 3) * 1024, 9, 511));
        flash_attn<<<dim3(8, 64), blk, 0, stream>>>(qkvb, 1536, qkvb + 512, 1536, vt,
                                                    ctxb, 512, SEQ);
        /* O-proj -> T1 (producer, stats for ln1) */
        prod(ctxb, 512, wa + (size_t)(12 + i) * 262144, 512, nullptr,
             xp32, xs, xg, xb, T1_32, T1_b, S_T1);
        /* FF1 (consumer of ln1) */
        g128(mkd(T1_b, 512, wf + (size_t)i * 1048576, 512, ffhb, 2048,
                 2048, 512, enc_ff1_b + i * 2048, 1, nullptr, 0,
                 S_T1, csF + (size_t)i * 4096, 11, 2047));
        /* FF2 -> T2[i&1] (producer, stats for ln2) */
        prod(ffhb, 2048, wf + (size_t)(8 + i) * 1048576, 2048, enc_ff2_b + i * 512,
             T1_32, S_T1, enc_ln1_g + i * 512, enc_ln1_b + i * 512,
             T2_32[i & 1], T2_b[i & 1], S_T2[i & 1]);
    }

    /* ===================== decoder ===================== */
    for (int i = 0; i < 4; ++i) {
        const ushort* xa = i ? T3_b[(i - 1) & 1] : dec0_b;
        const float2* xs = i ? S_T3[(i - 1) & 1] : nullptr;
        const float*  xp32 = i ? T3_32[(i - 1) & 1] : dec0_32;
        const float*  xg = i ? dec_ln3_g + (i - 1) * 512 : nullptr;
        const float*  xb = i ? dec_ln3_b + (i - 1) * 512 : nullptr;
        /* masked self-attention */
        g128(mkd(xa, 512, wa + (size_t)(16 + i * 3) * 262144, 512, qkvb, 1536,
                 1536, 512, nullptr, 0, vt, 1024, xs,
                 csA + (size_t)(16 + i * 3) * 1024, 9, 511));
        flash_attn<<<dim3(8, 64), blk, 0, stream>>>(qkvb, 1536, qkvb + 512, 1536, vt,
                                                    ctxb, 512, KLEN_MASKED);
        prod(ctxb, 512, wa + (size_t)(28 + i) * 262144, 512, nullptr,
             xp32, xs, xg, xb, U1_32, U1_b, S_U1);
        /* cross-attention: q-proj (ln1 of dec) + kv-proj (enc final) in one launch */
        {
            GDesc dq = mkd(U1_b, 512, wa + (size_t)(40 + i) * 262144, 512, qb, 512,
                           512, 512, nullptr, 0, nullptr, 0,
                           S_U1, csA + (size_t)(40 + i) * 1024, 9, 511);
            GDesc dkv = mkd(T2_b[1], 512, wa + (size_t)(32 + i * 2) * 262144, 512, kvb, 1024,
                            1024, 512, nullptr, 0, vt, 512,
                            S_T2[1], csA + (size_t)(32 + i * 2) * 1024, 9, 511);
            gemm_two<<<dim3(8, ROWS / 128, 2), blk, 0, stream>>>(dq, dkv);
        }
        flash_attn<<<dim3(8, 64), blk, 0, stream>>>(qb, 512, kvb, 1024, vt,
                                                    ctxb, 512, SEQ);
        prod(ctxb, 512, wa + (size_t)(44 + i) * 262144, 512, nullptr,
             U1_32, S_U1, dec_ln1_g + i * 512, dec_ln1_b + i * 512,
             U2_32, U2_b, S_U2);
        /* feed-forward */
        g128(mkd(U2_b, 512, wf + (size_t)(4 + i) * 1048576, 512, ffhb, 2048,
                 2048, 512, dec_ff1_b + i * 2048, 1, nullptr, 0,
                 S_U2, csF + (size_t)(4 + i) * 4096, 11, 2047));
        prod(ffhb, 2048, wf + (size_t)(12 + i) * 1048576, 2048, dec_ff2_b + i * 512,
             U2_32, S_U2, dec_ln2_g + i * 512, dec_ln2_b + i * 512,
             T3_32[i & 1], T3_b[i & 1], S_T3[i & 1]);
    }

    /* final projection (inline LN on T3[layer3]) */
    final_proj_ln<<<ROWS * 8 / 256, blk, 0, stream>>>(
        T3_32[1], S_T3[1], dec_ln3_g + 3 * 512, dec_ln3_b + 3 * 512,
        proj_w, proj_b, (float*)d_out);
}

// Round 8
// 1584.387 us; speedup vs baseline: 1.5698x; 1.0666x over previous
//
#include <hip/hip_runtime.h>
#include <hip/hip_bf16.h>
#include <math.h>

#define D_MODEL 512
#define N_HEADS 8
#define D_HEAD  64
#define D_FF    2048
#define SEQ     512
#define BATCH   8
#define ROWS    (BATCH * SEQ)          /* 4096 */
#define PRED_LEN 96
#define KLEN_MASKED (SEQ - PRED_LEN)   /* 416 */
#define LN_EPS  1e-5f

typedef float  f32x4 __attribute__((ext_vector_type(4)));
typedef short  s16x8 __attribute__((ext_vector_type(8)));

__device__ __forceinline__ float bf2f(ushort u) {
    union { unsigned int i; float f; } c; c.i = ((unsigned int)u) << 16; return c.f;
}
__device__ __forceinline__ ushort f2bf(float v) {
    __hip_bfloat16 h = __float2bfloat16(v);
    return *(ushort*)&h;
}
__device__ __forceinline__ void gl_lds16(const void* g, void* lds) {
    __builtin_amdgcn_global_load_lds(
        (const __attribute__((address_space(1))) unsigned int*)g,
        (__attribute__((address_space(3))) unsigned int*)lds, 16, 0, 0);
}

/* ==================== consumer GEMM (optional folded LN on A) ===============
 * C = [LN-corrected] A @ Bt^T + bias (opt relu).  BM=128, BK=32, 4 waves 2x2.
 * If statsA (4 partials): out = rs*P - rs*mu*sgamma[col] + cbeta[col] + bias.
 * VT-epilogue: blocks with n0>=vcol0 write per-head transposed V.
 */
struct GDesc {
    const ushort* A; int lda;
    const ushort* Bt; int ldb;
    ushort* C; int ldc;
    int N; int K;
    const float* bias; int relu;
    ushort* VT; int vcol0;
    const float2* statsA;   /* [4][4096] (sum, sumsq) partials; null = raw A */
    const float* cs;        /* [z][0..csN)=sgamma, [z][csN..2csN)=cbeta */
    int csShift; int csMask;
};

template<int BN>
__device__ __forceinline__ void cons_body(const GDesc& d)
{
    constexpr int NW = BN / 32;
    __shared__ __attribute__((aligned(16))) ushort As[128 * 32];
    __shared__ __attribute__((aligned(16))) ushort Bs[BN * 32];
    __shared__ float2 mrs[128];
    const int tid = threadIdx.x;
    const int w = tid >> 6, lane = tid & 63;
    const int l16 = lane & 15, quad = lane >> 4;
    const int m0 = blockIdx.y * 128, n0 = blockIdx.x * BN;
    if (d.statsA != nullptr && tid < 128) {
        float S = 0.f, Q = 0.f;
        #pragma unroll
        for (int j = 0; j < 4; ++j) {
            float2 pp = d.statsA[j * 4096 + m0 + tid];
            S += pp.x; Q += pp.y;
        }
        float mu = S * (1.f / 512.f);
        float var = Q * (1.f / 512.f) - mu * mu;
        mrs[tid] = make_float2(mu, rsqrtf(var + LN_EPS));
    }
    const ushort* Ab = d.A + (size_t)m0 * d.lda;
    const ushort* Bb = d.Bt + (size_t)n0 * d.ldb;
    const int wm = (w >> 1) * 64, wn = (w & 1) * (BN / 2);
    const int K = d.K;

    f32x4 acc[4][NW];
    #pragma unroll
    for (int i = 0; i < 4; ++i)
        #pragma unroll
        for (int j = 0; j < NW; ++j) acc[i][j] = (f32x4)0.f;

    for (int k0 = 0; k0 < K; k0 += 32) {
        #pragma unroll
        for (int t = 0; t < 2; ++t) {
            int c = (t * 4 + w) * 64 + lane;
            gl_lds16(Ab + (size_t)(c >> 2) * d.lda + k0 + (c & 3) * 8,
                     (void*)(As + (size_t)(t * 4 + w) * 512));
        }
        #pragma unroll
        for (int t = 0; t < BN / 64; ++t) {
            int c = (t * 4 + w) * 64 + lane;
            gl_lds16(Bb + (size_t)(c >> 2) * d.ldb + k0 + (c & 3) * 8,
                     (void*)(Bs + (size_t)(t * 4 + w) * 512));
        }
        __syncthreads();
        s16x8 af[4];
        #pragma unroll
        for (int i = 0; i < 4; ++i)
            af[i] = *(const s16x8*)(As + (size_t)(wm + i * 16 + l16) * 32 + quad * 8);
        #pragma unroll
        for (int j = 0; j < NW; ++j) {
            s16x8 bfr = *(const s16x8*)(Bs + (size_t)(wn + j * 16 + l16) * 32 + quad * 8);
            #pragma unroll
            for (int i = 0; i < 4; ++i)
                acc[i][j] = __builtin_amdgcn_mfma_f32_16x16x32_bf16(af[i], bfr, acc[i][j], 0, 0, 0);
        }
        __syncthreads();
    }
    const bool isv = (d.VT != nullptr) && (n0 >= d.vcol0);
    #pragma unroll
    for (int i = 0; i < 4; ++i) {
        #pragma unroll
        for (int j = 0; j < NW; ++j) {
            int col = n0 + wn + j * 16 + l16;
            float sg = 0.f, cb = 0.f;
            if (d.statsA) {
                int zi = col >> d.csShift;
                int off = col & d.csMask;
                const float* c0 = d.cs + (size_t)zi * 2 * (d.csMask + 1);
                sg = c0[off];
                cb = c0[d.csMask + 1 + off];
            }
            float bv = d.bias ? d.bias[col] : 0.f;
            float vv[4];
            #pragma unroll
            for (int r = 0; r < 4; ++r) {
                float v = acc[i][j][r];
                if (d.statsA) {
                    float2 m = mrs[wm + i * 16 + quad * 4 + r];
                    v = m.y * v - m.y * m.x * sg + cb;
                }
                v += bv;
                if (d.relu) v = fmaxf(v, 0.f);
                vv[r] = v;
            }
            if (isv) {
                int mrow = m0 + wm + i * 16 + quad * 4;
                int b = mrow >> 9, pbase = mrow & 511;
                int cv = col - d.vcol0;
                int h = cv >> 6, dd = cv & 63;
                union { ushort u[4]; uint2 v2; } pk;
                #pragma unroll
                for (int r = 0; r < 4; ++r) pk.u[r] = f2bf(vv[r]);
                *(uint2*)(d.VT + ((size_t)((b * 8 + h) * 64 + dd) * 512 + pbase)) = pk.v2;
            } else {
                #pragma unroll
                for (int r = 0; r < 4; ++r)
                    d.C[(size_t)(m0 + wm + i * 16 + quad * 4 + r) * d.ldc + col] = f2bf(vv[r]);
            }
        }
    }
}

template<int BN>
__global__ __launch_bounds__(256) void gemm_one(GDesc d)
{
    if ((int)(blockIdx.x * BN) < d.N) cons_body<BN>(d);
}

__global__ __launch_bounds__(256) void gemm_two(GDesc d0, GDesc d1)
{
    const GDesc& d = blockIdx.z ? d1 : d0;
    if ((int)(blockIdx.x * 128) < d.N) cons_body<128>(d);
}

/* ==================== producer GEMM: t = A@Bt^T + bias + y_prev =============
 * N=512 fixed. BM=64, BN=128, 512 threads (8 waves 2m x 4n, wave-tile 32x32),
 * grid (4, 64) = 256 blocks -> 2 waves/SIMD on all CUs (R7 had 1: 47us, 9% occ).
 * Writes fp32+bf16 carrier t and per-col-block row stats partials [4][4096].
 */
struct PDesc {
    const ushort* A; int lda;
    const ushort* Bt; int K;
    const float* bias;
    const float* prev32;
    const float2* statsP;
    const float* gprev; const float* bprev;
    float* t32; ushort* tb;
    float2* statsOut;           /* [4][4096] */
};

__global__ __launch_bounds__(512) void gemm_prod(PDesc d)
{
    __shared__ __attribute__((aligned(16))) ushort As[64 * 32];    /* 4KB */
    __shared__ __attribute__((aligned(16))) ushort Bs[128 * 32];   /* 8KB */
    __shared__ float2 mrsP[64];
    __shared__ float sS[4][64], sQ[4][64];
    const int tid = threadIdx.x;
    const int w = tid >> 6, lane = tid & 63;
    const int l16 = lane & 15, quad = lane >> 4;
    const int m0 = blockIdx.y * 64, n0 = blockIdx.x * 128;
    if (d.statsP != nullptr && tid < 64) {
        float S = 0.f, Q = 0.f;
        #pragma unroll
        for (int j = 0; j < 4; ++j) {
            float2 pp = d.statsP[j * 4096 + m0 + tid];
            S += pp.x; Q += pp.y;
        }
        float mu = S * (1.f / 512.f);
        float var = Q * (1.f / 512.f) - mu * mu;
        mrsP[tid] = make_float2(mu, rsqrtf(var + LN_EPS));
    }
    const ushort* Ab = d.A + (size_t)m0 * d.lda;
    const ushort* Bb = d.Bt + (size_t)n0 * d.K;
    const int wm = (w >> 2) * 32, wn = (w & 3) * 32;
    const int K = d.K;

    f32x4 acc[2][2];
    #pragma unroll
    for (int i = 0; i < 2; ++i)
        #pragma unroll
        for (int j = 0; j < 2; ++j) acc[i][j] = (f32x4)0.f;

    for (int k0 = 0; k0 < K; k0 += 32) {
        if (w < 4) {            /* A: 64x32 = 4KB = 4 wave-issues */
            int c = w * 64 + lane;
            gl_lds16(Ab + (size_t)(c >> 2) * d.lda + k0 + (c & 3) * 8,
                     (void*)(As + (size_t)w * 512));
        }
        {                       /* B: 128x32 = 8KB = 8 wave-issues */
            int c = w * 64 + lane;
            gl_lds16(Bb + (size_t)(c >> 2) * d.K + k0 + (c & 3) * 8,
                     (void*)(Bs + (size_t)w * 512));
        }
        __syncthreads();
        s16x8 af[2];
        #pragma unroll
        for (int i = 0; i < 2; ++i)
            af[i] = *(const s16x8*)(As + (size_t)(wm + i * 16 + l16) * 32 + quad * 8);
        #pragma unroll
        for (int j = 0; j < 2; ++j) {
            s16x8 bfr = *(const s16x8*)(Bs + (size_t)(wn + j * 16 + l16) * 32 + quad * 8);
            #pragma unroll
            for (int i = 0; i < 2; ++i)
                acc[i][j] = __builtin_amdgcn_mfma_f32_16x16x32_bf16(af[i], bfr, acc[i][j], 0, 0, 0);
        }
        __syncthreads();
    }

    int cols[2]; float bvv[2], gpv[2] = {0.f, 0.f}, bpv[2] = {0.f, 0.f};
    #pragma unroll
    for (int j = 0; j < 2; ++j) {
        cols[j] = n0 + wn + j * 16 + l16;
        bvv[j] = d.bias ? d.bias[cols[j]] : 0.f;
        if (d.statsP) { gpv[j] = d.gprev[cols[j]]; bpv[j] = d.bprev[cols[j]]; }
    }
    #pragma unroll
    for (int i = 0; i < 2; ++i) {
        #pragma unroll
        for (int r = 0; r < 4; ++r) {
            int rl = wm + i * 16 + quad * 4 + r;
            size_t grow = (size_t)(m0 + rl) * 512;
            float s = 0.f, q = 0.f;
            #pragma unroll
            for (int j = 0; j < 2; ++j) {
                float v = acc[i][j][r] + bvv[j];
                float pv = d.prev32[grow + cols[j]];
                float yp;
                if (d.statsP) {
                    float2 mp = mrsP[rl];
                    yp = (pv - mp.x) * mp.y * gpv[j] + bpv[j];
                } else yp = pv;
                float t = v + yp;
                d.t32[grow + cols[j]] = t;
                d.tb[grow + cols[j]] = f2bf(t);
                s += t; q += t * t;
            }
            s += __shfl_xor(s, 1); s += __shfl_xor(s, 2);
            s += __shfl_xor(s, 4); s += __shfl_xor(s, 8);
            q += __shfl_xor(q, 1); q += __shfl_xor(q, 2);
            q += __shfl_xor(q, 4); q += __shfl_xor(q, 8);
            if (l16 == 0) { sS[w & 3][rl] = s; sQ[w & 3][rl] = q; }
        }
    }
    __syncthreads();
    if (tid < 64)
        d.statsOut[blockIdx.x * 4096 + m0 + tid] =
            make_float2(sS[0][tid] + sS[1][tid] + sS[2][tid] + sS[3][tid],
                        sQ[0][tid] + sQ[1][tid] + sQ[2][tid] + sQ[3][tid]);
}

/* ==================== flash attention (unchanged, validated) ================ */
__global__ __launch_bounds__(256) void flash_attn(
    const ushort* __restrict__ Q, int ldq,
    const ushort* __restrict__ K, int ldk,
    const ushort* __restrict__ Vt,
    ushort* __restrict__ O, int ldo, int klen)
{
    __shared__ __attribute__((aligned(16))) ushort KVs[8192];
    __shared__ __attribute__((aligned(16))) ushort Es[4][2048];
    const int tid = threadIdx.x, w = tid >> 6, lane = tid & 63;
    const int l16 = lane & 15, quad = lane >> 4;
    const int bh = blockIdx.y, b = bh >> 3, h = bh & 7;
    const int q0 = blockIdx.x * 64;

    const ushort* Qb = Q + (size_t)(b * SEQ) * ldq + h * D_HEAD;
    const ushort* Kb = K + (size_t)(b * SEQ) * ldk + h * D_HEAD;

    s16x8 af0, af1;
    {
        const ushort* qr = Qb + (size_t)(q0 + w * 16 + l16) * ldq + quad * 8;
        af0 = *(const s16x8*)(qr);
        af1 = *(const s16x8*)(qr + 32);
    }

    f32x4 sc[32];

    #pragma unroll
    for (int kc = 0; kc < 4; ++kc) {
        #pragma unroll
        for (int it = 0; it < 4; ++it) {
            int cc = (it * 4 + w) * 64 + lane;
            int row = cc >> 3;
            int dch = (cc & 7) ^ (row & 7);
            gl_lds16(Kb + (size_t)(kc * 128 + row) * ldk + dch * 8,
                     (void*)(KVs + (size_t)(it * 4 + w) * 512));
        }
        __syncthreads();
        #pragma unroll
        for (int kt = 0; kt < 8; ++kt) {
            int r0 = kt * 16 + l16;
            s16x8 b0 = *(const s16x8*)(KVs + r0 * 64 + ((quad)     ^ (r0 & 7)) * 8);
            s16x8 b1 = *(const s16x8*)(KVs + r0 * 64 + ((4 + quad) ^ (r0 & 7)) * 8);
            f32x4 a = __builtin_amdgcn_mfma_f32_16x16x32_bf16(af0, b0, (f32x4)0.f, 0, 0, 0);
            sc[kc * 8 + kt] = __builtin_amdgcn_mfma_f32_16x16x32_bf16(af1, b1, a, 0, 0, 0);
        }
        __syncthreads();
    }

    float inv[4];
    #pragma unroll
    for (int r = 0; r < 4; ++r) {
        float m = -1e30f;
        #pragma unroll
        for (int j = 0; j < 32; ++j) {
            bool valid = (j * 16 + l16) < klen;
            m = valid ? fmaxf(m, sc[j][r]) : m;
        }
        m = fmaxf(m, __shfl_xor(m, 1));
        m = fmaxf(m, __shfl_xor(m, 2));
        m = fmaxf(m, __shfl_xor(m, 4));
        m = fmaxf(m, __shfl_xor(m, 8));
        float ssum = 0.f;
        #pragma unroll
        for (int j = 0; j < 32; ++j) {
            bool valid = (j * 16 + l16) < klen;
            float e = valid ? __expf((sc[j][r] - m) * 0.125f) : 0.f;
            sc[j][r] = e;
            ssum += e;
        }
        ssum += __shfl_xor(ssum, 1);
        ssum += __shfl_xor(ssum, 2);
        ssum += __shfl_xor(ssum, 4);
        ssum += __shfl_xor(ssum, 8);
        inv[r] = 1.f / ssum;
    }

    f32x4 oacc[4];
    #pragma unroll
    for (int jd = 0; jd < 4; ++jd) oacc[jd] = (f32x4)0.f;
    const ushort* Vb = Vt + (size_t)bh * (D_HEAD * SEQ);
    #pragma unroll
    for (int kc = 0; kc < 4; ++kc) {
        #pragma unroll
        for (int it = 0; it < 4; ++it) {
            int cc = (it * 4 + w) * 64 + lane;
            int dd = cc >> 4;
            int kch = (cc & 15) ^ (dd & 15);
            gl_lds16(Vb + (size_t)dd * SEQ + kc * 128 + kch * 8,
                     (void*)(KVs + (size_t)(it * 4 + w) * 512));
        }
        #pragma unroll
        for (int j = 0; j < 8; ++j) {
            int lcj = j * 2 + (l16 >> 3);
            #pragma unroll
            for (int r = 0; r < 4; ++r) {
                int m = quad * 4 + r;
                Es[w][m * 128 + (lcj ^ m) * 8 + (l16 & 7)] = f2bf(sc[kc * 8 + j][r]);
            }
        }
        __syncthreads();
        #pragma unroll
        for (int ks = 0; ks < 4; ++ks) {
            int lc = ks * 4 + quad;
            s16x8 ea = *(const s16x8*)(&Es[w][l16 * 128 + (lc ^ l16) * 8]);
            #pragma unroll
            for (int jd = 0; jd < 4; ++jd) {
                int row = jd * 16 + l16;
                s16x8 vb = *(const s16x8*)(KVs + row * 128 + (lc ^ l16) * 8);
                oacc[jd] = __builtin_amdgcn_mfma_f32_16x16x32_bf16(ea, vb, oacc[jd], 0, 0, 0);
            }
        }
        __syncthreads();
    }

    ushort* Ob = O + (size_t)(b * SEQ) * ldo + h * D_HEAD;
    #pragma unroll
    for (int jd = 0; jd < 4; ++jd)
        #pragma unroll
        for (int r = 0; r < 4; ++r)
            Ob[(size_t)(q0 + w * 16 + quad * 4 + r) * ldo + jd * 16 + l16] =
                f2bf(oacc[jd][r] * inv[r]);
}

/* ==================== weight repacks (+gamma scaling, +colsums) ============= */
struct AttnCtl { const float* w[48]; const float* g[48]; const float* b[48]; };
struct FfCtl   { const float* w[16]; const float* g[16]; const float* b[16]; };

__global__ __launch_bounds__(256) void repack_attn(AttnCtl L, ushort* __restrict__ out,
                                                   float* __restrict__ cs)
{
    int z = blockIdx.z;
    const float* in = L.w[z];
    const float* gz = L.g[z];
    const float* bz = L.b[z];
    ushort* o = out + (size_t)z * 262144;
    __shared__ float t[32][33];
    int n0 = blockIdx.x * 32, k0 = blockIdx.y * 32;
    int tx = threadIdx.x & 31, ty = threadIdx.x >> 5;
    #pragma unroll
    for (int r = 0; r < 4; ++r)
        t[ty + r * 8][tx] = in[(size_t)(k0 + ty + r * 8) * 512 + n0 + tx];
    __syncthreads();
    #pragma unroll
    for (int r = 0; r < 4; ++r) {
        int n = n0 + ty + r * 8, k = k0 + tx;
        float wv = t[tx][ty + r * 8];
        if (gz) {
            ushort wb = f2bf(wv * gz[k]);
            o[(size_t)n * 512 + k] = wb;
            float sgl = bf2f(wb);
            float cbl = wv * bz[k];
            #pragma unroll
            for (int m = 1; m < 32; m <<= 1) {
                sgl += __shfl_xor(sgl, m);
                cbl += __shfl_xor(cbl, m);
            }
            if (tx == 0) {
                atomicAdd(&cs[(size_t)z * 1024 + n], sgl);
                atomicAdd(&cs[(size_t)z * 1024 + 512 + n], cbl);
            }
        } else {
            o[(size_t)n * 512 + k] = f2bf(wv);
        }
    }
}

__global__ __launch_bounds__(256) void repack_ff(FfCtl L, ushort* __restrict__ out,
                                                 float* __restrict__ cs)
{
    int z = blockIdx.y;
    int Kd = (z < 8) ? 512 : 2048, Nd = (z < 8) ? 2048 : 512;
    const float* in = L.w[z];
    const float* gz = L.g[z];
    const float* bz = L.b[z];
    ushort* o = out + (size_t)z * (512 * 2048);
    int tt = blockIdx.x;
    int tn = Nd / 32;
    int n0 = (tt % tn) * 32, k0 = (tt / tn) * 32;
    __shared__ float ts[32][33];
    int tx = threadIdx.x & 31, ty = threadIdx.x >> 5;
    #pragma unroll
    for (int r = 0; r < 4; ++r)
        ts[ty + r * 8][tx] = in[(size_t)(k0 + ty + r * 8) * Nd + n0 + tx];
    __syncthreads();
    #pragma unroll
    for (int r = 0; r < 4; ++r) {
        int n = n0 + ty + r * 8, k = k0 + tx;
        float wv = ts[tx][ty + r * 8];
        if (gz) {
            ushort wb = f2bf(wv * gz[k]);
            o[(size_t)n * Kd + k] = wb;
            float sgl = bf2f(wb);
            float cbl = wv * bz[k];
            #pragma unroll
            for (int m = 1; m < 32; m <<= 1) {
                sgl += __shfl_xor(sgl, m);
                cbl += __shfl_xor(cbl, m);
            }
            if (tx == 0) {
                atomicAdd(&cs[(size_t)z * 4096 + n], sgl);
                atomicAdd(&cs[(size_t)z * 4096 + 2048 + n], cbl);
            }
        } else {
            o[(size_t)n * Kd + k] = f2bf(wv);
        }
    }
}

/* ==================== dual input projection ==================== */
__global__ __launch_bounds__(256) void input_proj2(
    const float* __restrict__ x0, const float* __restrict__ w0,
    const float* __restrict__ b0, const float* __restrict__ p0,
    float* __restrict__ o0_32, ushort* __restrict__ o0_b, int in0,
    const float* __restrict__ x1, const float* __restrict__ w1,
    const float* __restrict__ b1, const float* __restrict__ p1,
    float* __restrict__ o1_32, ushort* __restrict__ o1_b, int in1)
{
    const int z = blockIdx.y;
    const float* x = z ? x1 : x0;  const float* w = z ? w1 : w0;
    const float* bias = z ? b1 : b0; const float* pos = z ? p1 : p0;
    float* out32 = z ? o1_32 : o0_32; ushort* outb = z ? o1_b : o0_b;
    int in_size = z ? in1 : in0;
    int idx = blockIdx.x * 256 + threadIdx.x;
    int col = idx & (D_MODEL - 1);
    int row = idx >> 9;
    int l   = row & (SEQ - 1);
    const float* xr = x + (size_t)row * in_size;
    float acc = bias[col] + pos[(size_t)l * D_MODEL + col];
    for (int t = 0; t < in_size; ++t) acc += xr[t] * w[(size_t)t * D_MODEL + col];
    out32[idx] = acc;
    outb[idx]  = f2bf(acc);
}

/* ==================== final projection with inline LN ==================== */
__global__ __launch_bounds__(256) void final_proj_ln(
    const float* __restrict__ t32, const float2* __restrict__ stats,
    const float* __restrict__ g, const float* __restrict__ b,
    const float* __restrict__ W, const float* __restrict__ pb,
    float* __restrict__ out)
{
    int idx = blockIdx.x * 256 + threadIdx.x;
    int row = idx >> 3, c = idx & 7;
    float S = 0.f, Q = 0.f;
    #pragma unroll
    for (int j = 0; j < 4; ++j) {
        float2 pp = stats[j * 4096 + row];
        S += pp.x; Q += pp.y;
    }
    float mu = S * (1.f / 512.f);
    float rs = rsqrtf(Q * (1.f / 512.f) - mu * mu + LN_EPS);
    const float* tr = t32 + (size_t)row * 512;
    float acc = pb[c];
    for (int k = 0; k < 512; ++k) {
        float y = (tr[k] - mu) * rs * g[k] + b[k];
        acc += y * W[k * 8 + c];
    }
    out[idx] = acc;
}

/* ============================ host orchestration ============================ */
extern "C" void kernel_launch(void* const* d_in, const int* in_sizes, int n_in,
                              void* d_out, int out_size, void* d_ws, size_t ws_size,
                              hipStream_t stream)
{
    const float* src         = (const float*)d_in[0];
    const float* tgt         = (const float*)d_in[1];
    const float* src_pos     = (const float*)d_in[2];
    const float* tgt_pos     = (const float*)d_in[3];
    const float* src_lin_w   = (const float*)d_in[4];
    const float* src_lin_b   = (const float*)d_in[5];
    const float* tgt_lin_w   = (const float*)d_in[6];
    const float* tgt_lin_b   = (const float*)d_in[7];
    const float* enc_wq      = (const float*)d_in[8];
    const float* enc_wk      = (const float*)d_in[9];
    const float* enc_wv      = (const float*)d_in[10];
    const float* enc_wo      = (const float*)d_in[11];
    const float* enc_ff1_w   = (const float*)d_in[12];
    const float* enc_ff1_b   = (const float*)d_in[13];
    const float* enc_ff2_w   = (const float*)d_in[14];
    const float* enc_ff2_b   = (const float*)d_in[15];
    const float* enc_ln1_g   = (const float*)d_in[16];
    const float* enc_ln1_b   = (const float*)d_in[17];
    const float* enc_ln2_g   = (const float*)d_in[18];
    const float* enc_ln2_b   = (const float*)d_in[19];
    const float* dec_sa_wq   = (const float*)d_in[20];
    const float* dec_sa_wk   = (const float*)d_in[21];
    const float* dec_sa_wv   = (const float*)d_in[22];
    const float* dec_sa_wo   = (const float*)d_in[23];
    const float* dec_ca_wq   = (const float*)d_in[24];
    const float* dec_ca_wk   = (const float*)d_in[25];
    const float* dec_ca_wv   = (const float*)d_in[26];
    const float* dec_ca_wo   = (const float*)d_in[27];
    const float* dec_ff1_w   = (const float*)d_in[28];
    const float* dec_ff1_b   = (const float*)d_in[29];
    const float* dec_ff2_w   = (const float*)d_in[30];
    const float* dec_ff2_b   = (const float*)d_in[31];
    const float* dec_ln1_g   = (const float*)d_in[32];
    const float* dec_ln1_b   = (const float*)d_in[33];
    const float* dec_ln2_g   = (const float*)d_in[34];
    const float* dec_ln2_b   = (const float*)d_in[35];
    const float* dec_ln3_g   = (const float*)d_in[36];
    const float* dec_ln3_b   = (const float*)d_in[37];
    const float* proj_w      = (const float*)d_in[38];
    const float* proj_b      = (const float*)d_in[39];

    /* ---- workspace carve ---- */
    char* p = (char*)d_ws;
    auto carve = [&](size_t bytes) { char* r = p; p += (bytes + 255) & ~(size_t)255; return r; };
    const size_t C32 = (size_t)ROWS * 512 * 4, CB = (size_t)ROWS * 512 * 2;
    const size_t ST  = (size_t)4 * 4096 * sizeof(float2);
    float*  enc0_32 = (float*) carve(C32);  ushort* enc0_b = (ushort*)carve(CB);
    float*  dec0_32 = (float*) carve(C32);  ushort* dec0_b = (ushort*)carve(CB);
    float*  T1_32   = (float*) carve(C32);  ushort* T1_b   = (ushort*)carve(CB);
    float2* S_T1    = (float2*)carve(ST);
    float*  T2_32[2]; ushort* T2_b[2]; float2* S_T2[2];
    for (int i = 0; i < 2; ++i) {
        T2_32[i] = (float*)carve(C32); T2_b[i] = (ushort*)carve(CB);
        S_T2[i] = (float2*)carve(ST);
    }
    float*  U1_32   = (float*) carve(C32);  ushort* U1_b   = (ushort*)carve(CB);
    float2* S_U1    = (float2*)carve(ST);
    float*  U2_32   = (float*) carve(C32);  ushort* U2_b   = (ushort*)carve(CB);
    float2* S_U2    = (float2*)carve(ST);
    float*  T3_32[2]; ushort* T3_b[2]; float2* S_T3[2];
    for (int i = 0; i < 2; ++i) {
        T3_32[i] = (float*)carve(C32); T3_b[i] = (ushort*)carve(CB);
        S_T3[i] = (float2*)carve(ST);
    }
    ushort* qkvb = (ushort*)carve((size_t)ROWS * 1536 * 2);
    ushort* qb   = (ushort*)carve((size_t)ROWS * 512 * 2);
    ushort* kvb  = (ushort*)carve((size_t)ROWS * 1024 * 2);
    ushort* ctxb = (ushort*)carve((size_t)ROWS * 512 * 2);
    ushort* ffhb = (ushort*)carve((size_t)ROWS * D_FF * 2);
    ushort* vt   = (ushort*)carve((size_t)64 * D_HEAD * SEQ * 2);
    ushort* wa   = (ushort*)carve((size_t)48 * 262144 * 2);
    ushort* wf   = (ushort*)carve((size_t)16 * 1048576 * 2);
    float*  csA  = (float*) carve((size_t)(48 * 1024 + 16 * 4096) * 4);
    float*  csF  = csA + 48 * 1024;

    const dim3 blk(256);

    /* zero colsum accumulators (atomics target) */
    hipMemsetAsync(csA, 0, (size_t)(48 * 1024 + 16 * 4096) * 4, stream);

    /* ---- weight repack (2 launches) ---- */
    {
        AttnCtl A;
        for (int i = 0; i < 4; ++i) {
            const size_t o = (size_t)i * 262144;
            const float* g_qkv = (i == 0) ? nullptr : enc_ln2_g + (i - 1) * 512;
            const float* b_qkv = (i == 0) ? nullptr : enc_ln2_b + (i - 1) * 512;
            A.w[i * 3 + 0] = enc_wq + o;  A.g[i * 3 + 0] = g_qkv; A.b[i * 3 + 0] = b_qkv;
            A.w[i * 3 + 1] = enc_wk + o;  A.g[i * 3 + 1] = g_qkv; A.b[i * 3 + 1] = b_qkv;
            A.w[i * 3 + 2] = enc_wv + o;  A.g[i * 3 + 2] = g_qkv; A.b[i * 3 + 2] = b_qkv;
            A.w[12 + i] = enc_wo + o;     A.g[12 + i] = nullptr;  A.b[12 + i] = nullptr;
            const float* g_sa = (i == 0) ? nullptr : dec_ln3_g + (i - 1) * 512;
            const float* b_sa = (i == 0) ? nullptr : dec_ln3_b + (i - 1) * 512;
            A.w[16 + i * 3 + 0] = dec_sa_wq + o; A.g[16 + i * 3 + 0] = g_sa; A.b[16 + i * 3 + 0] = b_sa;
            A.w[16 + i * 3 + 1] = dec_sa_wk + o; A.g[16 + i * 3 + 1] = g_sa; A.b[16 + i * 3 + 1] = b_sa;
            A.w[16 + i * 3 + 2] = dec_sa_wv + o; A.g[16 + i * 3 + 2] = g_sa; A.b[16 + i * 3 + 2] = b_sa;
            A.w[28 + i] = dec_sa_wo + o;  A.g[28 + i] = nullptr;  A.b[28 + i] = nullptr;
            A.w[32 + i * 2 + 0] = dec_ca_wk + o; A.g[32 + i * 2 + 0] = enc_ln2_g + 3 * 512;
            A.b[32 + i * 2 + 0] = enc_ln2_b + 3 * 512;
            A.w[32 + i * 2 + 1] = dec_ca_wv + o; A.g[32 + i * 2 + 1] = enc_ln2_g + 3 * 512;
            A.b[32 + i * 2 + 1] = enc_ln2_b + 3 * 512;
            A.w[40 + i] = dec_ca_wq + o;  A.g[40 + i] = dec_ln1_g + i * 512;
            A.b[40 + i] = dec_ln1_b + i * 512;
            A.w[44 + i] = dec_ca_wo + o;  A.g[44 + i] = nullptr;  A.b[44 + i] = nullptr;
        }
        repack_attn<<<dim3(16, 16, 48), blk, 0, stream>>>(A, wa, csA);
        FfCtl F;
        for (int i = 0; i < 4; ++i) {
            F.w[0 + i]  = enc_ff1_w + (size_t)i * 1048576;
            F.g[0 + i]  = enc_ln1_g + i * 512;  F.b[0 + i] = enc_ln1_b + i * 512;
            F.w[4 + i]  = dec_ff1_w + (size_t)i * 1048576;
            F.g[4 + i]  = dec_ln2_g + i * 512;  F.b[4 + i] = dec_ln2_b + i * 512;
            F.w[8 + i]  = enc_ff2_w + (size_t)i * 1048576;
            F.g[8 + i]  = nullptr;              F.b[8 + i] = nullptr;
            F.w[12 + i] = dec_ff2_w + (size_t)i * 1048576;
            F.g[12 + i] = nullptr;              F.b[12 + i] = nullptr;
        }
        repack_ff<<<dim3(1024, 16), blk, 0, stream>>>(F, wf, csF);
    }

    auto mkd = [&](const ushort* A, int lda, const ushort* Bt, int ldb,
                   ushort* C, int ldc, int N, int K, const float* bias, int relu,
                   ushort* VT, int vcol0, const float2* statsA,
                   const float* cs, int csShift, int csMask) {
        GDesc d; d.A = A; d.lda = lda; d.Bt = Bt; d.ldb = ldb;
        d.C = C; d.ldc = ldc; d.N = N; d.K = K;
        d.bias = bias; d.relu = relu; d.VT = VT; d.vcol0 = vcol0;
        d.statsA = statsA; d.cs = cs; d.csShift = csShift; d.csMask = csMask;
        return d;
    };
    auto g128 = [&](const GDesc& d) {
        gemm_one<128><<<dim3(d.N / 128, ROWS / 128), blk, 0, stream>>>(d);
    };
    auto prod = [&](const ushort* A, int lda, const ushort* Bt, int K,
                    const float* bias, const float* prev32, const float2* statsP,
                    const float* gprev, const float* bprev,
                    float* t32, ushort* tb, float2* statsOut) {
        PDesc d; d.A = A; d.lda = lda; d.Bt = Bt; d.K = K;
        d.bias = bias; d.prev32 = prev32; d.statsP = statsP;
        d.gprev = gprev; d.bprev = bprev;
        d.t32 = t32; d.tb = tb; d.statsOut = statsOut;
        gemm_prod<<<dim3(4, 64), dim3(512), 0, stream>>>(d);
    };

    /* input projections (raw carriers, no LN) */
    input_proj2<<<dim3(ROWS * 512 / 256, 2), blk, 0, stream>>>(
        src, src_lin_w, src_lin_b, src_pos, enc0_32, enc0_b, 16,
        tgt, tgt_lin_w, tgt_lin_b, tgt_pos, dec0_32, dec0_b, 8);

    /* ===================== encoder ===================== */
    for (int i = 0; i < 4; ++i) {
        const ushort* xa = i ? T2_b[(i - 1) & 1] : enc0_b;
        const float2* xs = i ? S_T2[(i - 1) & 1] : nullptr;
        const float*  xp32 = i ? T2_32[(i - 1) & 1] : enc0_32;
        const float*  xg = i ? enc_ln2_g + (i - 1) * 512 : nullptr;
        const float*  xb = i ? enc_ln2_b + (i - 1) * 512 : nullptr;
        /* QKV */
        g128(mkd(xa, 512, wa + (size_t)(i * 3) * 262144, 512, qkvb, 1536,
                 1536, 512, nullptr, 0, vt, 1024, xs, csA + (size_t)(i * 3) * 1024, 9, 511));
        flash_attn<<<dim3(8, 64), blk, 0, stream>>>(qkvb, 1536, qkvb + 512, 1536, vt,
                                                    ctxb, 512, SEQ);
        /* O-proj -> T1 (producer, stats for ln1) */
        prod(ctxb, 512, wa + (size_t)(12 + i) * 262144, 512, nullptr,
             xp32, xs, xg, xb, T1_32, T1_b, S_T1);
        /* FF1 (consumer of ln1) */
        g128(mkd(T1_b, 512, wf + (size_t)i * 1048576, 512, ffhb, 2048,
                 2048, 512, enc_ff1_b + i * 2048, 1, nullptr, 0,
                 S_T1, csF + (size_t)i * 4096, 11, 2047));
        /* FF2 -> T2[i&1] (producer, stats for ln2) */
        prod(ffhb, 2048, wf + (size_t)(8 + i) * 1048576, 2048, enc_ff2_b + i * 512,
             T1_32, S_T1, enc_ln1_g + i * 512, enc_ln1_b + i * 512,
             T2_32[i & 1], T2_b[i & 1], S_T2[i & 1]);
    }

    /* ===================== decoder ===================== */
    for (int i = 0; i < 4; ++i) {
        const ushort* xa = i ? T3_b[(i - 1) & 1] : dec0_b;
        const float2* xs = i ? S_T3[(i - 1) & 1] : nullptr;
        const float*  xp32 = i ? T3_32[(i - 1) & 1] : dec0_32;
        const float*  xg = i ? dec_ln3_g + (i - 1) * 512 : nullptr;
        const float*  xb = i ? dec_ln3_b + (i - 1) * 512 : nullptr;
        /* masked self-attention */
        g128(mkd(xa, 512, wa + (size_t)(16 + i * 3) * 262144, 512, qkvb, 1536,
                 1536, 512, nullptr, 0, vt, 1024, xs,
                 csA + (size_t)(16 + i * 3) * 1024, 9, 511));
        flash_attn<<<dim3(8, 64), blk, 0, stream>>>(qkvb, 1536, qkvb + 512, 1536, vt,
                                                    ctxb, 512, KLEN_MASKED);
        prod(ctxb, 512, wa + (size_t)(28 + i) * 262144, 512, nullptr,
             xp32, xs, xg, xb, U1_32, U1_b, S_U1);
        /* cross-attention: q-proj (ln1 of dec) + kv-proj (enc final) in one launch */
        {
            GDesc dq = mkd(U1_b, 512, wa + (size_t)(40 + i) * 262144, 512, qb, 512,
                           512, 512, nullptr, 0, nullptr, 0,
                           S_U1, csA + (size_t)(40 + i) * 1024, 9, 511);
            GDesc dkv = mkd(T2_b[1], 512, wa + (size_t)(32 + i * 2) * 262144, 512, kvb, 1024,
                            1024, 512, nullptr, 0, vt, 512,
                            S_T2[1], csA + (size_t)(32 + i * 2) * 1024, 9, 511);
            gemm_two<<<dim3(8, ROWS / 128, 2), blk, 0, stream>>>(dq, dkv);
        }
        flash_attn<<<dim3(8, 64), blk, 0, stream>>>(qb, 512, kvb, 1024, vt,
                                                    ctxb, 512, SEQ);
        prod(ctxb, 512, wa + (size_t)(44 + i) * 262144, 512, nullptr,
             U1_32, S_U1, dec_ln1_g + i * 512, dec_ln1_b + i * 512,
             U2_32, U2_b, S_U2);
        /* feed-forward */
        g128(mkd(U2_b, 512, wf + (size_t)(4 + i) * 1048576, 512, ffhb, 2048,
                 2048, 512, dec_ff1_b + i * 2048, 1, nullptr, 0,
                 S_U2, csF + (size_t)(4 + i) * 4096, 11, 2047));
        prod(ffhb, 2048, wf + (size_t)(12 + i) * 1048576, 2048, dec_ff2_b + i * 512,
             U2_32, S_U2, dec_ln2_g + i * 512, dec_ln2_b + i * 512,
             T3_32[i & 1], T3_b[i & 1], S_T3[i & 1]);
    }

    /* final projection (inline LN on T3[layer3]) */
    final_proj_ln<<<ROWS * 8 / 256, blk, 0, stream>>>(
        T3_32[1], S_T3[1], dec_ln3_g + 3 * 512, dec_ln3_b + 3 * 512,
        proj_w, proj_b, (float*)d_out);
}